// Round 7
// baseline (29773.322 us; speedup 1.0000x reference)
//
#include <hip/hip_runtime.h>

// ---------------------------------------------------------------------------
// Decoder_49005576847865 — persistent single-kernel incremental decoder.
//   B=16, d=512, H=8 (dh=64), L=4, dff=2048, Lenc=2048, 16 steps, vocab=256.
// Round 7: kill the L2-miss traffic that bounded round 6 (~470 GB/s on 3 GB).
//   * enc LDS-RESIDENT: each flash block keeps its (b,chunk) 128-key slice
//     as bf16 in LDS for the whole kernel (32 MB across 256 CUs). Cross-attn
//     reads zero enc bytes from memory after P0.
//   * batch-shared GEMVs: one weight slice per block, all 16 batch rows in
//     LDS bf16; split-K reduced in-wave by shfl (wave == batch row). Weight
//     slices have fixed block mapping -> L2-resident across steps.
// ---------------------------------------------------------------------------

typedef unsigned short ushort_t;
typedef __attribute__((ext_vector_type(4))) float f32x4;
typedef __attribute__((ext_vector_type(8))) unsigned short us8;
typedef __attribute__((ext_vector_type(4))) unsigned short us4;

#define NB 256
#define NTHR 1024

__device__ __forceinline__ float bf2f(ushort_t u) {
    union { unsigned int i; float f; } v; v.i = ((unsigned int)u) << 16; return v.f;
}
__device__ __forceinline__ ushort_t f2bf(float f) {
    union { unsigned int i; float f; } v; v.f = f;
    return (ushort_t)((v.i + 0x7FFF + ((v.i >> 16) & 1)) >> 16);   // RNE
}
__device__ __forceinline__ float wave_sum(float v) {
    #pragma unroll
    for (int m = 32; m; m >>= 1) v += __shfl_xor(v, m);
    return v;
}
__device__ __forceinline__ float wave_max(float v) {
    #pragma unroll
    for (int m = 32; m; m >>= 1) v = fmaxf(v, __shfl_xor(v, m));
    return v;
}

// ---- coherent (agent-scope, fence-free) access for mutable activations -----
union U64C { unsigned long long u; float2 f; };
__device__ __forceinline__ float clf(const float* p) {
    return __hip_atomic_load(p, __ATOMIC_RELAXED, __HIP_MEMORY_SCOPE_AGENT);
}
__device__ __forceinline__ void csf(float* p, float v) {
    __hip_atomic_store(p, v, __ATOMIC_RELAXED, __HIP_MEMORY_SCOPE_AGENT);
}
__device__ __forceinline__ void csf2(float* p, float x, float y) {
    U64C c; c.f.x = x; c.f.y = y;
    __hip_atomic_store((unsigned long long*)p, c.u, __ATOMIC_RELAXED,
                       __HIP_MEMORY_SCOPE_AGENT);
}

// ---- fence-free grid barrier (round-5 protocol, verified) ------------------
__device__ __forceinline__ void gsync(unsigned* bar) {
    __syncthreads();
    if (threadIdx.x == 0) {
        unsigned grp = blockIdx.x & 7u;
        unsigned* sub = bar + 32 + grp * 32;
        unsigned* rel = bar + 32 * 9;
        unsigned s = __hip_atomic_fetch_add(sub, 1u, __ATOMIC_RELAXED,
                                            __HIP_MEMORY_SCOPE_AGENT);
        unsigned e = s >> 5;
        bool fin = false;
        if ((s & 31u) == 31u) {
            unsigned a = __hip_atomic_fetch_add(bar, 1u, __ATOMIC_RELAXED,
                                                __HIP_MEMORY_SCOPE_AGENT);
            if ((a & 7u) == 7u) {
                #pragma unroll
                for (int i = 0; i < 8; i++)
                    __hip_atomic_store(rel + i * 32, e + 1u, __ATOMIC_RELAXED,
                                       __HIP_MEMORY_SCOPE_AGENT);
                fin = true;
            }
        }
        if (!fin) {
            unsigned* myrel = rel + grp * 32;
            while ((int)(__hip_atomic_load(myrel, __ATOMIC_RELAXED,
                                           __HIP_MEMORY_SCOPE_AGENT) - (e + 1u)) < 0)
                __builtin_amdgcn_s_sleep(2);
        }
    }
    __syncthreads();
}

struct Args {
    const float *enc, *encIn, *embW, *embB, *outW, *outB;
    const float *selfW, *selfB, *crossW, *crossB;
    const float *fW1, *fb1, *fW2, *fb2, *lng, *lnb;
    float* out;
    unsigned* bar;
    float *pos, *x0, *qbuf, *y1, *y2, *y3, *attnb;
    float *lnx, *lny1, *lny2, *qt, *Pm2, *Ps2, *Pz, *tmpb, *selfK, *selfV;
};

// ---- LN of 16 rows (wave==row) from global(coherent) -> xsb bf16 [16][512].
// Optionally write fp32 LN'd slices [i0,i1) (64 cols each) to lnout (csf).
__device__ __forceinline__ void ln16_bf(const float* __restrict__ src,
                                        const float* __restrict__ g,
                                        const float* __restrict__ be,
                                        int use_ln, ushort_t* xsb,
                                        float* lnout, int i0, int i1) {
    int row = threadIdx.x >> 6, lane = threadIdx.x & 63;
    const float* rp = src + (size_t)row * 512;
    float loc[8];
    float s = 0.f;
    #pragma unroll
    for (int i = 0; i < 8; i++) { loc[i] = clf(rp + lane + i * 64); s += loc[i]; }
    if (use_ln) {
        s = wave_sum(s);
        float mu = s * (1.f / 512.f);
        float var = 0.f;
        #pragma unroll
        for (int i = 0; i < 8; i++) { float d = loc[i] - mu; var += d * d; }
        var = wave_sum(var);
        float rstd = rsqrtf(var * (1.f / 512.f) + 1e-6f);
        #pragma unroll
        for (int i = 0; i < 8; i++) {
            int c = lane + i * 64;
            loc[i] = (loc[i] - mu) * rstd * g[c] + be[c];
        }
    }
    #pragma unroll
    for (int i = 0; i < 8; i++) xsb[row * 512 + lane + i * 64] = f2bf(loc[i]);
    if (lnout) {
        for (int i = i0; i < i1; i++)
            csf(lnout + (size_t)row * 512 + i * 64 + lane, loc[i]);
    }
    __syncthreads();
}

// ---- batch-shared GEMV: 64 cols (col0..+63), K=512, all 16 b at once.
// thread = (qc:4bits, ksl:2bits, b:4bits); wave == one b. Result (f32x4 for
// cols col0+qc*4) valid on ALL lanes after shfl reduce.
__device__ __forceinline__ f32x4 gemv512(const ushort_t* xsb,
                                         const float* __restrict__ W,
                                         int ldw, int col0) {
    int tid = threadIdx.x;
    int qc = tid & 15, ksl = (tid >> 4) & 3, b = tid >> 6;
    const float* Wp = W + (size_t)(ksl * 128) * ldw + col0 + qc * 4;
    const ushort_t* xp = xsb + b * 512 + ksl * 128;
    f32x4 acc = {0.f, 0.f, 0.f, 0.f};
    #pragma unroll 2
    for (int r8 = 0; r8 < 16; r8++) {
        us8 xv = *(const us8*)(xp + r8 * 8);
        #pragma unroll
        for (int j = 0; j < 8; j++) {
            f32x4 wv = *(const f32x4*)(Wp + (size_t)(r8 * 8 + j) * ldw);
            acc += bf2f(xv[j]) * wv;
        }
    }
    #pragma unroll
    for (int j = 0; j < 4; j++) {
        acc[j] += __shfl_xor(acc[j], 16);
        acc[j] += __shfl_xor(acc[j], 32);
    }
    return acc;
}

// ---------------------------------------------------------------------------

__global__ __launch_bounds__(NTHR, 4) void k_mega(Args A) {
    __shared__ ushort_t encL[65536];   // 128 keys x 512, bf16 — PERSISTENT
    __shared__ float padL[128];        // pad flags for this block's keys
    __shared__ float scratch[6144];    // 24 KB stage scratch
    const int bid = blockIdx.x, tid = threadIdx.x;
    const int myb = bid >> 4, myc = bid & 15;   // flash role (fixed)
    ushort_t* xsb = (ushort_t*)scratch;          // [16][512] bf16 view

    // ---------------- P0: enc->LDS, pad flags, posenc ----------------------
    {
        const float* ep = A.enc + ((size_t)myb * 2048 + myc * 128) * 512;
        #pragma unroll 4
        for (int it = 0; it < 16; it++) {
            int idx = tid + it * 1024;            // us4 chunk index
            float4 v = *(const float4*)(ep + (size_t)idx * 4);
            us4 o; o[0] = f2bf(v.x); o[1] = f2bf(v.y); o[2] = f2bf(v.z); o[3] = f2bf(v.w);
            *(us4*)(encL + idx * 4) = o;
        }
        int key = tid >> 3, sub = tid & 7;
        const float* p = A.encIn + ((size_t)myb * 2048 + myc * 128 + key) * 128 + sub * 16;
        int ok = 1;
        #pragma unroll
        for (int j = 0; j < 4; j++) {
            float4 v = *(const float4*)(p + j * 4);
            ok &= (v.x == 0.f) & (v.y == 0.f) & (v.z == 0.f) & (v.w == 0.f);
        }
        ok &= __shfl_xor(ok, 1); ok &= __shfl_xor(ok, 2); ok &= __shfl_xor(ok, 4);
        if (sub == 0) padL[key] = ok ? 1.f : 0.f;
        if (bid < 8) {
            int idx = bid * 1024 + tid;
            int pp = idx >> 9, i = idx & 511;
            float expo = (2.0f * (float)(i >> 1)) * (1.f / 512.f);
            float ang = (float)pp * powf(10000.0f, -expo);
            csf(A.pos + idx, ((i & 1) == 0) ? sinf(ang) : cosf(ang));
        }
    }
    gsync(A.bar);

    for (int t = 0; t < 16; t++) {
        // ---------------- S_emb: x0 = tok@embW*sqrt(d)+pos (4 blocks) ------
        if (bid < 4) {
            int cb = bid;                         // 128-col slice
            ushort_t* tokb = (ushort_t*)scratch;  // [16][256]
            #pragma unroll
            for (int it = 0; it < 4; it++) {
                int idx = tid + it * 1024;        // b*256+col
                tokb[idx] = (t == 0) ? f2bf(1.f)
                    : f2bf(clf(A.out + (size_t)(idx >> 8) * 4096 + (t - 1) * 256 + (idx & 255)));
            }
            __syncthreads();
            int qc = tid & 31, ksl = (tid >> 5) & 1, b = tid >> 6;
            const float* Wp = A.embW + (size_t)(ksl * 128) * 512 + cb * 128 + qc * 4;
            const ushort_t* xp = tokb + b * 256 + ksl * 128;
            f32x4 acc = {0.f, 0.f, 0.f, 0.f};
            #pragma unroll 2
            for (int r8 = 0; r8 < 16; r8++) {
                us8 xv = *(const us8*)(xp + r8 * 8);
                #pragma unroll
                for (int j = 0; j < 8; j++) {
                    f32x4 wv = *(const f32x4*)(Wp + (size_t)(r8 * 8 + j) * 512);
                    acc += bf2f(xv[j]) * wv;
                }
            }
            #pragma unroll
            for (int j = 0; j < 4; j++) acc[j] += __shfl_xor(acc[j], 32);
            if (ksl == 0) {
                int col = cb * 128 + qc * 4;
                #pragma unroll
                for (int j = 0; j < 4; j++)
                    csf(A.x0 + (size_t)b * 512 + col + j,
                        (acc[j] + A.embB[col + j]) * 22.627416997969522f
                        + A.pos[t * 512 + col + j]);
            }
        }
        gsync(A.bar);

        for (int l = 0; l < 4; l++) {
            const float* src = (l == 0) ? A.x0 : A.y3;
            const float* gP = (l == 0) ? A.lng : A.lng + ((l - 1) * 3 + 2) * 512;
            const float* bP = (l == 0) ? A.lnb : A.lnb + ((l - 1) * 3 + 2) * 512;
            int ulnP = (l != 0);

            // ---------------- S1: q/k/v projections (24 blocks) ------------
            if (bid < 24) {
                int m = bid >> 3, cb = bid & 7;
                ln16_bf(src, gP, bP, ulnP, xsb,
                        (m == 0) ? A.lnx : nullptr, cb, cb + 1);
                f32x4 acc = gemv512(xsb, A.selfW + ((size_t)(l * 4 + m)) * 262144,
                                    512, cb * 64);
                if (((tid >> 4) & 3) == 0) {
                    int b = tid >> 6, col = cb * 64 + (tid & 15) * 4;
                    const float* bias = A.selfB + (l * 4 + m) * 512 + col;
                    float* dst = (m == 0) ? (A.qbuf + (size_t)b * 512 + col)
                               : ((m == 1) ? A.selfK : A.selfV)
                                 + (((size_t)l * 16 + b) * 16 + t) * 512 + col;
                    #pragma unroll
                    for (int j = 0; j < 4; j++) csf(dst + j, acc[j] + bias[j]);
                }
            }
            gsync(A.bar);

            // ---------------- S2: self-attn + Wo + residual (8 blocks) -----
            if (bid < 8) {
                int cb = bid;
                float* lg = scratch + 4096;     // [16][8][16]
                #pragma unroll
                for (int it = 0; it < 8; it++) {
                    int idx = tid + it * 1024;
                    xsb[idx] = f2bf(clf(A.qbuf + idx));   // q staged bf16
                }
                __syncthreads();
                #pragma unroll
                for (int it = 0; it < 2; it++) {
                    int b = it * 8 + (tid >> 7);
                    int h = (tid >> 4) & 7, j = tid & 15;
                    if (j <= t) {
                        const ushort_t* qp = xsb + b * 512 + h * 64;
                        const float* kp = A.selfK
                            + ((((size_t)l * 16 + b) * 16 + j)) * 512 + h * 64;
                        float s = 0.f;
                        #pragma unroll
                        for (int d = 0; d < 64; d++) s += bf2f(qp[d]) * clf(kp + d);
                        lg[(b * 8 + h) * 16 + j] = s * 0.125f;
                    }
                }
                __syncthreads();
                if (tid < 128) {
                    int bh = tid;
                    float m = -1e30f;
                    for (int j = 0; j <= t; j++) m = fmaxf(m, lg[bh * 16 + j]);
                    float ssum = 0.f;
                    for (int j = 0; j <= t; j++) {
                        float e = __expf(lg[bh * 16 + j] - m);
                        lg[bh * 16 + j] = e; ssum += e;
                    }
                    float inv = 1.f / ssum;
                    for (int j = 0; j <= t; j++) lg[bh * 16 + j] *= inv;
                }
                __syncthreads();
                {   // av -> xsb (overwrite q staging)
                    int b = tid >> 6, d0 = (tid & 63) * 8;
                    int h = d0 >> 6;
                    float av[8] = {0, 0, 0, 0, 0, 0, 0, 0};
                    for (int j = 0; j <= t; j++) {
                        float w = lg[(b * 8 + h) * 16 + j];
                        const float* vp = A.selfV
                            + (((size_t)l * 16 + b) * 16 + j) * 512 + d0;
                        #pragma unroll
                        for (int k = 0; k < 8; k++) av[k] += w * clf(vp + k);
                    }
                    __syncthreads();
                    #pragma unroll
                    for (int k = 0; k < 8; k++) xsb[b * 512 + d0 + k] = f2bf(av[k]);
                }
                __syncthreads();
                f32x4 acc = gemv512(xsb, A.selfW + ((size_t)(l * 4 + 3)) * 262144,
                                    512, cb * 64);
                if (((tid >> 4) & 3) == 0) {
                    int b = tid >> 6, col = cb * 64 + (tid & 15) * 4;
                    #pragma unroll
                    for (int j = 0; j < 4; j++)
                        csf(A.y1 + (size_t)b * 512 + col + j,
                            acc[j] + A.selfB[(l * 4 + 3) * 512 + col + j]
                            + clf(A.lnx + (size_t)b * 512 + col + j));
                }
            }
            gsync(A.bar);

            // ---------------- S34: qc_h + qt_h (8 blocks = heads) ----------
            if (bid < 8) {
                int h = bid;
                float* qchA = scratch + 4096;   // [16][64]
                ln16_bf(A.y1, A.lng + (l * 3) * 512, A.lnb + (l * 3) * 512, 1,
                        xsb, (h == 0) ? A.lny1 : nullptr, 0, (h == 0) ? 8 : 0);
                f32x4 acc = gemv512(xsb, A.crossW + ((size_t)(l * 4)) * 262144,
                                    512, h * 64);
                if (((tid >> 4) & 3) == 0) {
                    int b = tid >> 6, qc = tid & 15;
                    #pragma unroll
                    for (int j = 0; j < 4; j++)
                        qchA[b * 64 + qc * 4 + j] =
                            acc[j] + A.crossB[(l * 4) * 512 + h * 64 + qc * 4 + j];
                }
                __syncthreads();
                {   // qt[b][h][D] = 0.125 * qch . Wk[D][h*64..]
                    int D = tid >> 1, half = tid & 1;
                    const float* wr = A.crossW + ((size_t)(l * 4 + 1)) * 262144
                                    + (size_t)D * 512 + h * 64 + half * 32;
                    float wreg[32];
                    #pragma unroll
                    for (int j = 0; j < 32; j += 4) {
                        f32x4 wv = *(const f32x4*)(wr + j);
                        wreg[j] = wv[0]; wreg[j+1] = wv[1]; wreg[j+2] = wv[2]; wreg[j+3] = wv[3];
                    }
                    #pragma unroll 4
                    for (int b = 0; b < 16; b++) {
                        const float* qp = qchA + b * 64 + half * 32;
                        float a = 0.f;
                        #pragma unroll
                        for (int j = 0; j < 32; j++) a += qp[j] * wreg[j];
                        a += __shfl_xor(a, 1);
                        if (half == 0)
                            csf(A.qt + ((size_t)b * 8 + h) * 512 + D, a * 0.125f);
                    }
                }
            }
            gsync(A.bar);

            // ---------------- S5: flash cross-attn from LDS (all 256) ------
            {
                float* qts = scratch;           // [8][520]
                float* lge = scratch + 4160;    // [8][128]
                float* wms = scratch + 5184;    // [16]
                float* wss = scratch + 5200;    // [16]
                #pragma unroll
                for (int it = 0; it < 4; it++) {
                    int idx = tid + it * 1024;
                    qts[(idx >> 9) * 520 + (idx & 511)] =
                        clf(A.qt + (size_t)myb * 4096 + idx);
                }
                __syncthreads();
                #pragma unroll
                for (int it = 0; it < 4; it++) {
                    int key = it * 32 + (tid >> 5);
                    int hh = (tid >> 2) & 7, part = tid & 3;
                    const ushort_t* er = encL + key * 512;
                    const float* q = qts + hh * 520;
                    float a0 = 0.f, a1 = 0.f;
                    #pragma unroll
                    for (int ch = 0; ch < 16; ch++) {
                        int c8 = (part + ch * 4) * 8;
                        us8 ev8 = *(const us8*)(er + c8);
                        const float* qp = q + c8;
                        a0 += bf2f(ev8[0])*qp[0] + bf2f(ev8[1])*qp[1]
                            + bf2f(ev8[2])*qp[2] + bf2f(ev8[3])*qp[3];
                        a1 += bf2f(ev8[4])*qp[4] + bf2f(ev8[5])*qp[5]
                            + bf2f(ev8[6])*qp[6] + bf2f(ev8[7])*qp[7];
                    }
                    float acc = a0 + a1;
                    acc += __shfl_xor(acc, 1);
                    acc += __shfl_xor(acc, 2);
                    if (part == 0)
                        lge[hh * 128 + key] = (padL[key] != 0.f) ? -2e30f : acc;
                }
                __syncthreads();
                {   // single-shot softmax over 128 keys (wave = half a head)
                    int hh = tid >> 7, k = tid & 127;
                    float lv = lge[hh * 128 + k];
                    float mv = wave_max(lv);
                    if ((tid & 63) == 0) wms[tid >> 6] = mv;
                    __syncthreads();
                    float m = fmaxf(wms[hh * 2], wms[hh * 2 + 1]);
                    float ev = __expf(lv - m);
                    float sv = wave_sum(ev);
                    if ((tid & 63) == 0) wss[tid >> 6] = sv;
                    lge[hh * 128 + k] = ev;
                    __syncthreads();
                    if (tid < 8) {
                        int bc = myb * 16 + myc;
                        csf(A.Pm2 + bc * 8 + tid, fmaxf(wms[tid * 2], wms[tid * 2 + 1]));
                        csf(A.Ps2 + bc * 8 + tid, wss[tid * 2] + wss[tid * 2 + 1]);
                    }
                }
                __syncthreads();
                {   // z = sum_k ev * enc_k (from LDS)
                    int hz = tid >> 7, ii = tid & 127;
                    f32x4 z = {0.f, 0.f, 0.f, 0.f};
                    const ushort_t* ep = encL + ii * 4;
                    const float* le = lge + hz * 128;
                    #pragma unroll 4
                    for (int k = 0; k < 128; k++) {
                        float ev = le[k];
                        us4 e4 = *(const us4*)(ep + k * 512);
                        z[0] += ev * bf2f(e4[0]); z[1] += ev * bf2f(e4[1]);
                        z[2] += ev * bf2f(e4[2]); z[3] += ev * bf2f(e4[3]);
                    }
                    float* dst = A.Pz + ((size_t)((myb * 16 + myc) * 8 + hz)) * 512 + ii * 4;
                    csf2(dst, z[0], z[1]);
                    csf2(dst + 2, z[2], z[3]);
                }
            }
            gsync(A.bar);

            // ---------------- S6: combine chunks + @Wv (8 blocks) ----------
            if (bid < 8) {
                int h = bid;
                float* ecs = scratch + 4096;    // [16][16]
                float* inv = scratch + 4352;    // [16]
                if (tid < 256) {
                    int b = tid >> 4, cc = tid & 15;
                    float mcv = clf(A.Pm2 + (b * 16 + cc) * 8 + h);
                    float m = mcv;
                    m = fmaxf(m, __shfl_xor(m, 1)); m = fmaxf(m, __shfl_xor(m, 2));
                    m = fmaxf(m, __shfl_xor(m, 4)); m = fmaxf(m, __shfl_xor(m, 8));
                    float ec = __expf(mcv - m);
                    float sv = ec * clf(A.Ps2 + (b * 16 + cc) * 8 + h);
                    sv += __shfl_xor(sv, 1); sv += __shfl_xor(sv, 2);
                    sv += __shfl_xor(sv, 4); sv += __shfl_xor(sv, 8);
                    ecs[b * 16 + cc] = ec;
                    if (cc == 0) inv[b] = 1.f / sv;
                }
                __syncthreads();
                {
                    int b = tid >> 6, d0 = (tid & 63) * 8;
                    float iv = inv[b];
                    #pragma unroll
                    for (int j = 0; j < 8; j++) {
                        float a = 0.f;
                        #pragma unroll
                        for (int cc = 0; cc < 16; cc++)
                            a += ecs[b * 16 + cc]
                               * clf(A.Pz + ((size_t)((b * 16 + cc) * 8 + h)) * 512 + d0 + j);
                        xsb[b * 512 + d0 + j] = f2bf(a * iv);
                    }
                }
                __syncthreads();
                f32x4 acc = gemv512(xsb, A.crossW + ((size_t)(l * 4 + 2)) * 262144,
                                    512, h * 64);
                if (((tid >> 4) & 3) == 0) {
                    int b = tid >> 6, col = h * 64 + (tid & 15) * 4;
                    #pragma unroll
                    for (int j = 0; j < 4; j++)
                        csf(A.attnb + (size_t)b * 512 + col + j,
                            acc[j] + A.crossB[(l * 4 + 2) * 512 + col + j]);
                }
            }
            gsync(A.bar);

            // ---------------- S7: y2 = attnb@Wco + bco + lny1 (8 blocks) ---
            if (bid < 8) {
                int cb = bid;
                #pragma unroll
                for (int it = 0; it < 8; it++) {
                    int idx = tid + it * 1024;
                    xsb[idx] = f2bf(clf(A.attnb + idx));
                }
                __syncthreads();
                f32x4 acc = gemv512(xsb, A.crossW + ((size_t)(l * 4 + 3)) * 262144,
                                    512, cb * 64);
                if (((tid >> 4) & 3) == 0) {
                    int b = tid >> 6, col = cb * 64 + (tid & 15) * 4;
                    #pragma unroll
                    for (int j = 0; j < 4; j++)
                        csf(A.y2 + (size_t)b * 512 + col + j,
                            acc[j] + A.crossB[(l * 4 + 3) * 512 + col + j]
                            + clf(A.lny1 + (size_t)b * 512 + col + j));
                }
            }
            gsync(A.bar);

            // ---------------- S8: tmpb = relu(LN(y2)@W1+b1) (32 blocks) ----
            if (bid < 32) {
                int cb = bid;
                ln16_bf(A.y2, A.lng + (l * 3 + 1) * 512, A.lnb + (l * 3 + 1) * 512,
                        1, xsb, (cb < 8) ? A.lny2 : nullptr, cb, cb + 1);
                f32x4 acc = gemv512(xsb, A.fW1 + (size_t)l * 512 * 2048,
                                    2048, cb * 64);
                if (((tid >> 4) & 3) == 0) {
                    int b = tid >> 6, col = cb * 64 + (tid & 15) * 4;
                    #pragma unroll
                    for (int j = 0; j < 4; j++)
                        csf(A.tmpb + (size_t)b * 2048 + col + j,
                            fmaxf(acc[j] + A.fb1[l * 2048 + col + j], 0.f));
                }
            }
            gsync(A.bar);

            // ---------------- S9: y3 = tmpb@W2+b2+lny2 (32 blocks) ---------
            if (bid < 32) {
                int cb = bid;                    // 16-col slice
                int qc = tid & 3, ksl = (tid >> 2) & 15, b = tid >> 6;
                const float* Wp = A.fW2 + (size_t)l * 2048 * 512
                                + (size_t)(ksl * 128) * 512 + cb * 16 + qc * 4;
                const float* xp = A.tmpb + (size_t)b * 2048 + ksl * 128;
                f32x4 acc = {0.f, 0.f, 0.f, 0.f};
                #pragma unroll 8
                for (int r = 0; r < 128; r++) {
                    f32x4 wv = *(const f32x4*)(Wp + (size_t)r * 512);
                    acc += clf(xp + r) * wv;
                }
                #pragma unroll
                for (int j = 0; j < 4; j++) {
                    acc[j] += __shfl_xor(acc[j], 4);
                    acc[j] += __shfl_xor(acc[j], 8);
                    acc[j] += __shfl_xor(acc[j], 16);
                    acc[j] += __shfl_xor(acc[j], 32);
                }
                if (ksl == 0) {
                    int col = cb * 16 + qc * 4;
                    #pragma unroll
                    for (int j = 0; j < 4; j++)
                        csf(A.y3 + (size_t)b * 512 + col + j,
                            acc[j] + A.fb2[l * 512 + col + j]
                            + clf(A.lny2 + (size_t)b * 512 + col + j));
                }
            }
            gsync(A.bar);
        } // l

        // ---------------- S_out: logits (4 blocks) ----------------
        if (bid < 4) {
            int cb = bid;
            ln16_bf(A.y3, A.lng + 11 * 512, A.lnb + 11 * 512, 1, xsb,
                    nullptr, 0, 0);
            f32x4 acc = gemv512(xsb, A.outW, 256, cb * 64);
            if (((tid >> 4) & 3) == 0) {
                int b = tid >> 6, col = cb * 64 + (tid & 15) * 4;
                #pragma unroll
                for (int j = 0; j < 4; j++)
                    csf(A.out + (size_t)b * 4096 + t * 256 + col + j,
                        acc[j] + A.outB[col + j]);
            }
        }
        gsync(A.bar);
    } // t
}

// ---------------------------------------------------------------------------

extern "C" void kernel_launch(void* const* d_in, const int* in_sizes, int n_in,
                              void* d_out, int out_size, void* d_ws, size_t ws_size,
                              hipStream_t stream) {
    Args A;
    A.enc    = (const float*)d_in[0];
    A.encIn  = (const float*)d_in[1];
    A.embW   = (const float*)d_in[2];
    A.embB   = (const float*)d_in[3];
    A.outW   = (const float*)d_in[4];
    A.outB   = (const float*)d_in[5];
    A.selfW  = (const float*)d_in[6];
    A.selfB  = (const float*)d_in[7];
    A.crossW = (const float*)d_in[8];
    A.crossB = (const float*)d_in[9];
    A.fW1    = (const float*)d_in[10];
    A.fb1    = (const float*)d_in[11];
    A.fW2    = (const float*)d_in[12];
    A.fb2    = (const float*)d_in[13];
    A.lng    = (const float*)d_in[14];
    A.lnb    = (const float*)d_in[15];
    A.out    = (float*)d_out;

    char* ws = (char*)d_ws;
    size_t off = 0;
    auto alloc = [&](size_t bytes) -> char* {
        char* p = ws + off;
        off = (off + bytes + 255) & ~(size_t)255;
        return p;
    };
    char* barrier = alloc(4096);
    A.bar = (unsigned*)barrier;
    A.pos   = (float*)alloc(16 * 512 * 4);
    A.x0    = (float*)alloc(16 * 512 * 4);
    A.qbuf  = (float*)alloc(16 * 512 * 4);
    A.y1    = (float*)alloc(16 * 512 * 4);
    A.y2    = (float*)alloc(16 * 512 * 4);
    A.y3    = (float*)alloc(16 * 512 * 4);
    A.attnb = (float*)alloc(16 * 512 * 4);
    A.lnx   = (float*)alloc(16 * 512 * 4);
    A.lny1  = (float*)alloc(16 * 512 * 4);
    A.lny2  = (float*)alloc(16 * 512 * 4);
    A.qt    = (float*)alloc((size_t)16 * 8 * 512 * 4);
    A.Pm2   = (float*)alloc(16 * 16 * 8 * 4);
    A.Ps2   = (float*)alloc(16 * 16 * 8 * 4);
    A.Pz    = (float*)alloc((size_t)16 * 16 * 8 * 512 * 4);
    A.tmpb  = (float*)alloc((size_t)16 * 2048 * 4);
    A.selfK = (float*)alloc((size_t)4 * 16 * 16 * 512 * 4);
    A.selfV = (float*)alloc((size_t)4 * 16 * 16 * 512 * 4);
    if (off > ws_size) return;   // ~9 MB — always fits

    hipMemsetAsync(barrier, 0, 4096, stream);
    k_mega<<<dim3(NB), dim3(NTHR), 0, stream>>>(A);
}

// Round 8
// 8142.836 us; speedup vs baseline: 3.6564x; 3.6564x over previous
//
#include <hip/hip_runtime.h>

// ---------------------------------------------------------------------------
// Decoder_49005576847865 — persistent single-kernel incremental decoder.
//   B=16, d=512, H=8 (dh=64), L=4, dff=2048, Lenc=2048, 16 steps, vocab=256.
// Round 8: round-6 structure (proven 9.7ms) + ONE change: enc is LDS-resident
//   (each block holds its (b,chunk) 128-key slice bf16 + pad flags for the
//   whole kernel). S5 flash reads zero enc bytes from memory. All GEMV
//   stages, block mappings, and the fence-free barrier are round-6 verbatim.
// ---------------------------------------------------------------------------

typedef unsigned short ushort_t;
typedef __attribute__((ext_vector_type(4))) float f32x4;
typedef __attribute__((ext_vector_type(8))) unsigned short us8;
typedef __attribute__((ext_vector_type(4))) unsigned short us4;

#define NB 256
#define NTHR 1024

__device__ __forceinline__ float bf2f(ushort_t u) {
    union { unsigned int i; float f; } v; v.i = ((unsigned int)u) << 16; return v.f;
}
__device__ __forceinline__ ushort_t f2bf(float f) {
    union { unsigned int i; float f; } v; v.f = f;
    return (ushort_t)((v.i + 0x7FFF + ((v.i >> 16) & 1)) >> 16);   // RNE
}
__device__ __forceinline__ float wave_sum(float v) {
    #pragma unroll
    for (int m = 32; m; m >>= 1) v += __shfl_xor(v, m);
    return v;
}
__device__ __forceinline__ float wave_max(float v) {
    #pragma unroll
    for (int m = 32; m; m >>= 1) v = fmaxf(v, __shfl_xor(v, m));
    return v;
}

// ---- coherent (agent-scope, fence-free) access for MUTABLE activations -----
union U64C { unsigned long long u; float2 f; };
__device__ __forceinline__ float clf(const float* p) {
    return __hip_atomic_load(p, __ATOMIC_RELAXED, __HIP_MEMORY_SCOPE_AGENT);
}
__device__ __forceinline__ void csf(float* p, float v) {
    __hip_atomic_store(p, v, __ATOMIC_RELAXED, __HIP_MEMORY_SCOPE_AGENT);
}
__device__ __forceinline__ float2 clf2(const float* p) {
    U64C c; c.u = __hip_atomic_load((unsigned long long*)p, __ATOMIC_RELAXED,
                                    __HIP_MEMORY_SCOPE_AGENT);
    return c.f;
}
__device__ __forceinline__ void csf2(float* p, float x, float y) {
    U64C c; c.f.x = x; c.f.y = y;
    __hip_atomic_store((unsigned long long*)p, c.u, __ATOMIC_RELAXED,
                       __HIP_MEMORY_SCOPE_AGENT);
}

// ---- fence-free grid barrier (rounds 5-7 protocol, verified) ---------------
__device__ __forceinline__ void gsync(unsigned* bar) {
    __syncthreads();
    if (threadIdx.x == 0) {
        unsigned grp = blockIdx.x & 7u;
        unsigned* sub = bar + 32 + grp * 32;
        unsigned* rel = bar + 32 * 9;
        unsigned s = __hip_atomic_fetch_add(sub, 1u, __ATOMIC_RELAXED,
                                            __HIP_MEMORY_SCOPE_AGENT);
        unsigned e = s >> 5;
        bool fin = false;
        if ((s & 31u) == 31u) {
            unsigned a = __hip_atomic_fetch_add(bar, 1u, __ATOMIC_RELAXED,
                                                __HIP_MEMORY_SCOPE_AGENT);
            if ((a & 7u) == 7u) {
                #pragma unroll
                for (int i = 0; i < 8; i++)
                    __hip_atomic_store(rel + i * 32, e + 1u, __ATOMIC_RELAXED,
                                       __HIP_MEMORY_SCOPE_AGENT);
                fin = true;
            }
        }
        if (!fin) {
            unsigned* myrel = rel + grp * 32;
            while ((int)(__hip_atomic_load(myrel, __ATOMIC_RELAXED,
                                           __HIP_MEMORY_SCOPE_AGENT) - (e + 1u)) < 0)
                __builtin_amdgcn_s_sleep(2);
        }
    }
    __syncthreads();
}

// ---- block-wide LN of one 512 row (1024 threads; first 512 carry data) -----
__device__ __forceinline__ void ln512b(const float* __restrict__ row,
                                       const float* __restrict__ g,
                                       const float* __restrict__ be,
                                       int use_ln, float* dst, float* red) {
    int tid = threadIdx.x;
    float a = (tid < 512) ? clf(row + tid) : 0.f;
    if (use_ln) {
        float s = wave_sum(a);
        if ((tid & 63) == 0) red[tid >> 6] = s;
        __syncthreads();
        float tot = 0.f;
        #pragma unroll
        for (int i = 0; i < 16; i++) tot += red[i];
        float mu = tot * (1.f / 512.f);
        float d = (tid < 512) ? (a - mu) : 0.f;
        float v = wave_sum(d * d);
        __syncthreads();
        if ((tid & 63) == 0) red[tid >> 6] = v;
        __syncthreads();
        float vt = 0.f;
        #pragma unroll
        for (int i = 0; i < 16; i++) vt += red[i];
        float rstd = rsqrtf(vt * (1.f / 512.f) + 1e-6f);
        if (tid < 512) dst[tid] = d * rstd * g[tid] + be[tid];
    } else {
        if (tid < 512) dst[tid] = a;
    }
    __syncthreads();
}

// ---- block GEMV core: NC=NCQ*4 cols, S k-slices of KS rows (NCQ*S=1024) ----
template<int NCQ, int S, int KS>
__device__ __forceinline__ void gemv_block(const float* xs, const float* __restrict__ W,
                                           int ldw, int col0, float* part) {
    int tid = threadIdx.x;
    int ct = tid & (NCQ - 1);
    int ks = tid / NCQ;
    int colq = col0 + ct * 4;
    const float* Wp = W + (size_t)(ks * KS) * ldw + colq;
    const float* xp = xs + ks * KS;
    f32x4 acc = {0.f, 0.f, 0.f, 0.f};
    #pragma unroll 8
    for (int r = 0; r < KS; r++) {
        f32x4 wv = *(const f32x4*)(Wp + (size_t)r * ldw);
        acc += xp[r] * wv;
    }
    *(f32x4*)(part + ks * (NCQ * 4) + ct * 4) = acc;
    __syncthreads();
}
template<int NC, int S>
__device__ __forceinline__ float gemv_reduce(const float* part) {
    int tid = threadIdx.x;   // caller ensures tid < NC
    float acc = 0.f;
    #pragma unroll
    for (int s = 0; s < S; s++) acc += part[s * NC + tid];
    return acc;
}

struct Args {
    const float *enc, *encIn, *embW, *embB, *outW, *outB;
    const float *selfW, *selfB, *crossW, *crossB;
    const float *fW1, *fb1, *fW2, *fb2, *lng, *lnb;
    float* out;
    unsigned* bar;
    float *pos, *x0, *qbuf, *y1, *y2, *y3, *attnb;
    float *lny1, *lny2, *qt, *Pm2, *Ps2, *Pz, *tmpb, *selfK, *selfV;
};

// ---------------------------------------------------------------------------

__global__ __launch_bounds__(NTHR, 1) void k_mega(Args A) {
    __shared__ ushort_t encL[65536];   // this block's 128-key enc slice (bf16)
    __shared__ float padL[128];        // this block's pad flags — persistent
    __shared__ float sm[6400];         // stage scratch (25.6 KB)
    const int bid = blockIdx.x, tid = threadIdx.x;
    const int myb = bid >> 4, myc = bid & 15;    // flash role (fixed)
    float* red = sm + 1792;
    float* part = sm + 2048;

    // ---------------- P0: enc->LDS, pad flags, posenc ----------------------
    {
        const float* ep = A.enc + ((size_t)myb * 2048 + myc * 128) * 512;
        #pragma unroll 4
        for (int it = 0; it < 16; it++) {
            int idx = tid + it * 1024;            // us4 chunk index (16384)
            float4 v = *(const float4*)(ep + (size_t)idx * 4);
            us4 o; o[0] = f2bf(v.x); o[1] = f2bf(v.y); o[2] = f2bf(v.z); o[3] = f2bf(v.w);
            *(us4*)(encL + idx * 4) = o;
        }
        int key = tid >> 3, sub = tid & 7;
        const float* p = A.encIn + ((size_t)myb * 2048 + myc * 128 + key) * 128 + sub * 16;
        int ok = 1;
        #pragma unroll
        for (int j = 0; j < 4; j++) {
            float4 v = *(const float4*)(p + j * 4);
            ok &= (v.x == 0.f) & (v.y == 0.f) & (v.z == 0.f) & (v.w == 0.f);
        }
        ok &= __shfl_xor(ok, 1); ok &= __shfl_xor(ok, 2); ok &= __shfl_xor(ok, 4);
        if (sub == 0) padL[key] = ok ? 1.f : 0.f;
        if (bid < 8) {   // positional encodings: 16*512
            int idx = bid * 1024 + tid;
            int pp = idx >> 9, i = idx & 511;
            float expo = (2.0f * (float)(i >> 1)) * (1.f / 512.f);
            float ang = (float)pp * powf(10000.0f, -expo);
            csf(A.pos + idx, ((i & 1) == 0) ? sinf(ang) : cosf(ang));
        }
    }
    gsync(A.bar);

    for (int t = 0; t < 16; t++) {
        // ---------------- S_emb: x0 = tok@embW*sqrt(d)+pos ----------------
        if (bid < 16) {
            int b = bid;
            float* tok = sm;
            if (tid < 256)
                tok[tid] = (t == 0) ? 1.f
                         : clf(A.out + (size_t)b * 4096 + (t - 1) * 256 + tid);
            __syncthreads();
            gemv_block<128, 8, 32>(tok, A.embW, 512, 0, part);
            if (tid < 512) {
                float acc = gemv_reduce<512, 8>(part) + A.embB[tid];
                csf(A.x0 + (size_t)b * 512 + tid,
                    acc * 22.627416997969522f + clf(A.pos + t * 512 + tid));
            }
        }
        gsync(A.bar);

        for (int l = 0; l < 4; l++) {
            const float* src = (l == 0) ? A.x0 : A.y3;
            const float* gP = (l == 0) ? nullptr : A.lng + ((l - 1) * 3 + 2) * 512;
            const float* bP = (l == 0) ? nullptr : A.lnb + ((l - 1) * 3 + 2) * 512;
            int ulnP = (l != 0);

            // ---------------- S1: self q/k/v projections -------------------
            if (bid < 96) {
                int m = bid >> 5, r = bid & 31;
                int b = r >> 1, ch = r & 1;
                float* xs = sm;
                ln512b(src + (size_t)b * 512, gP, bP, ulnP, xs, red);
                gemv_block<64, 16, 32>(xs, A.selfW + ((size_t)(l * 4 + m)) * 262144,
                                       512, ch * 256, part);
                if (tid < 256) {
                    int col = ch * 256 + tid;
                    float acc = gemv_reduce<256, 16>(part) + A.selfB[(l * 4 + m) * 512 + col];
                    if (m == 0) csf(A.qbuf + (size_t)b * 512 + col, acc);
                    else if (m == 1)
                        csf(A.selfK + (((size_t)l * 16 + b) * 16 + t) * 512 + col, acc);
                    else
                        csf(A.selfV + (((size_t)l * 16 + b) * 16 + t) * 512 + col, acc);
                }
            }
            gsync(A.bar);

            // ---------------- S2: self-attn + Wo proj + residual -----------
            if (bid < 32) {
                int b = bid >> 1, ch = bid & 1;
                float* xr = sm; float* qs = sm + 512; float* as_ = sm + 1024;
                float* lg = sm + 1536; float* wsv = sm + 1664;
                ln512b(src + (size_t)b * 512, gP, bP, ulnP, xr, red);
                if (tid < 512) qs[tid] = clf(A.qbuf + (size_t)b * 512 + tid);
                __syncthreads();
                const float* Kb = A.selfK + ((size_t)l * 16 + b) * 16 * 512;
                const float* Vb = A.selfV + ((size_t)l * 16 + b) * 16 * 512;
                if (tid < 128) {
                    int h = tid >> 4, j = tid & 15;
                    if (j <= t) {
                        const float* kr_ = Kb + (size_t)j * 512 + h * 64;
                        const float* qh_ = qs + h * 64;
                        float s0 = 0.f, s1 = 0.f;
                        #pragma unroll
                        for (int d = 0; d < 64; d += 4) {
                            float2 qa = *(const float2*)(qh_ + d);
                            float2 qb = *(const float2*)(qh_ + d + 2);
                            float2 ka = clf2(kr_ + d);
                            float2 kb = clf2(kr_ + d + 2);
                            s0 += qa.x * ka.x + qa.y * ka.y;
                            s1 += qb.x * kb.x + qb.y * kb.y;
                        }
                        lg[h * 16 + j] = (s0 + s1) * 0.125f;
                    }
                }
                __syncthreads();
                if (tid < 8) {
                    float m = -1e30f;
                    for (int j = 0; j <= t; j++) m = fmaxf(m, lg[tid * 16 + j]);
                    float ssum = 0.f;
                    for (int j = 0; j <= t; j++) {
                        float e = __expf(lg[tid * 16 + j] - m);
                        wsv[tid * 16 + j] = e; ssum += e;
                    }
                    float inv = 1.f / ssum;
                    for (int j = 0; j <= t; j++) wsv[tid * 16 + j] *= inv;
                }
                __syncthreads();
                if (tid < 512) {
                    int h = tid >> 6;
                    float a = 0.f;
                    for (int j = 0; j <= t; j++)
                        a += wsv[h * 16 + j] * clf(Vb + (size_t)j * 512 + tid);
                    as_[tid] = a;
                }
                __syncthreads();
                gemv_block<64, 16, 32>(as_, A.selfW + ((size_t)(l * 4 + 3)) * 262144,
                                       512, ch * 256, part);
                if (tid < 256) {
                    int col = ch * 256 + tid;
                    float acc = gemv_reduce<256, 16>(part);
                    csf(A.y1 + (size_t)b * 512 + col,
                        acc + A.selfB[(l * 4 + 3) * 512 + col] + xr[col]);
                }
            }
            gsync(A.bar);

            // ---------------- S34: qc_h then qt (merged) -------------------
            if (bid < 128) {
                int b = bid >> 3, h = bid & 7;
                float* xsw = sm;
                float* qch = sm + 1824;   // 64
                ln512b(A.y1 + (size_t)b * 512, A.lng + (l * 3) * 512,
                       A.lnb + (l * 3) * 512, 1, xsw, red);
                if (h == 0 && tid < 512)
                    csf(A.lny1 + (size_t)b * 512 + tid, xsw[tid]);
                gemv_block<16, 64, 8>(xsw, A.crossW + ((size_t)(l * 4)) * 262144,
                                      512, h * 64, part);
                if (tid < 64)
                    qch[tid] = gemv_reduce<64, 64>(part) + A.crossB[(l * 4) * 512 + h * 64 + tid];
                __syncthreads();
                {   // qt[b,h,D] = 0.125 * qch . Wk[D][h*64..]
                    int D = tid >> 1, half = tid & 1;
                    const float* wr = A.crossW + ((size_t)(l * 4 + 1)) * 262144
                                    + (size_t)D * 512 + h * 64 + half * 32;
                    const float* qp = qch + half * 32;
                    float a0 = 0.f, a1 = 0.f;
                    #pragma unroll
                    for (int j = 0; j < 8; j += 2) {
                        f32x4 w0 = *(const f32x4*)(wr + j * 4);
                        f32x4 w1 = *(const f32x4*)(wr + j * 4 + 4);
                        a0 += qp[j*4]*w0[0] + qp[j*4+1]*w0[1] + qp[j*4+2]*w0[2] + qp[j*4+3]*w0[3];
                        a1 += qp[j*4+4]*w1[0] + qp[j*4+5]*w1[1] + qp[j*4+6]*w1[2] + qp[j*4+7]*w1[3];
                    }
                    float v = a0 + a1;
                    v += __shfl_xor(v, 1);
                    if (half == 0)
                        csf(A.qt + ((size_t)b * 8 + h) * 512 + D, v * 0.125f);
                }
            }
            gsync(A.bar);

            // ---------------- S5: flash cross-attn from LDS (all 256) ------
            {
                float* qts = sm;            // [8][520]
                float* lge = sm + 4160;     // [8][128]
                float* wms = sm + 5184;     // [16]
                float* wss = sm + 5200;     // [16]
                #pragma unroll
                for (int it = 0; it < 4; it++) {
                    int idx = tid + it * 1024;
                    qts[(idx >> 9) * 520 + (idx & 511)] =
                        clf(A.qt + (size_t)myb * 4096 + idx);
                }
                __syncthreads();
                #pragma unroll
                for (int it = 0; it < 4; it++) {
                    int key = it * 32 + (tid >> 5);
                    int hh = (tid >> 2) & 7, pq = tid & 3;
                    const ushort_t* er = encL + key * 512;
                    const float* q = qts + hh * 520;
                    float a0 = 0.f, a1 = 0.f;
                    #pragma unroll
                    for (int ch = 0; ch < 16; ch++) {
                        int c8 = (pq + ch * 4) * 8;
                        us8 ev8 = *(const us8*)(er + c8);
                        const float* qp = q + c8;
                        a0 += bf2f(ev8[0])*qp[0] + bf2f(ev8[1])*qp[1]
                            + bf2f(ev8[2])*qp[2] + bf2f(ev8[3])*qp[3];
                        a1 += bf2f(ev8[4])*qp[4] + bf2f(ev8[5])*qp[5]
                            + bf2f(ev8[6])*qp[6] + bf2f(ev8[7])*qp[7];
                    }
                    float acc = a0 + a1;
                    acc += __shfl_xor(acc, 1);
                    acc += __shfl_xor(acc, 2);
                    if (pq == 0)
                        lge[hh * 128 + key] = (padL[key] != 0.f) ? -2e30f : acc;
                }
                __syncthreads();
                {   // single-shot softmax over 128 keys (wave = half a head)
                    int hh = tid >> 7, k = tid & 127;
                    float lv = lge[hh * 128 + k];
                    float mv = wave_max(lv);
                    if ((tid & 63) == 0) wms[tid >> 6] = mv;
                    __syncthreads();
                    float m = fmaxf(wms[hh * 2], wms[hh * 2 + 1]);
                    float ev = __expf(lv - m);
                    float sv = wave_sum(ev);
                    if ((tid & 63) == 0) wss[tid >> 6] = sv;
                    lge[hh * 128 + k] = ev;
                    __syncthreads();
                    if (tid < 8) {
                        int bc = myb * 16 + myc;
                        csf(A.Pm2 + bc * 8 + tid, fmaxf(wms[tid * 2], wms[tid * 2 + 1]));
                        csf(A.Ps2 + bc * 8 + tid, wss[tid * 2] + wss[tid * 2 + 1]);
                    }
                }
                __syncthreads();
                {   // z = sum_k ev * enc_k (from LDS)
                    int hz = tid >> 7, ii = tid & 127;
                    f32x4 z = {0.f, 0.f, 0.f, 0.f};
                    const ushort_t* ep2 = encL + ii * 4;
                    const float* le = lge + hz * 128;
                    #pragma unroll 4
                    for (int k = 0; k < 128; k++) {
                        float ev = le[k];
                        us4 e4 = *(const us4*)(ep2 + k * 512);
                        z[0] += ev * bf2f(e4[0]); z[1] += ev * bf2f(e4[1]);
                        z[2] += ev * bf2f(e4[2]); z[3] += ev * bf2f(e4[3]);
                    }
                    float* dst = A.Pz + ((size_t)((myb * 16 + myc) * 8 + hz)) * 512 + ii * 4;
                    csf2(dst, z[0], z[1]);
                    csf2(dst + 2, z[2], z[3]);
                }
            }
            gsync(A.bar);

            // ---------------- S6: combine chunks + @Wv ---------------------
            if (bid < 128) {
                int b = bid >> 3, h = bid & 7;
                float* zs = sm;           // 512
                float* zs2 = sm + 512;    // 2 x 512
                float* ecs = sm + 1600;   // 17
                if (tid < 16) {
                    float mcv = clf(A.Pm2 + (b * 16 + tid) * 8 + h);
                    float mm = mcv;
                    mm = fmaxf(mm, __shfl_xor(mm, 1));
                    mm = fmaxf(mm, __shfl_xor(mm, 2));
                    mm = fmaxf(mm, __shfl_xor(mm, 4));
                    mm = fmaxf(mm, __shfl_xor(mm, 8));
                    float ec = __expf(mcv - mm);
                    float sv = ec * clf(A.Ps2 + (b * 16 + tid) * 8 + h);
                    sv += __shfl_xor(sv, 1); sv += __shfl_xor(sv, 2);
                    sv += __shfl_xor(sv, 4); sv += __shfl_xor(sv, 8);
                    ecs[tid] = ec;
                    if (tid == 0) ecs[16] = 1.f / sv;
                }
                __syncthreads();
                {
                    int D = tid & 511, chf = tid >> 9;
                    float a = 0.f;
                    #pragma unroll
                    for (int j = 0; j < 8; j++) {
                        int cc = chf * 8 + j;
                        a += ecs[cc] * clf(A.Pz + ((size_t)(b * 16 + cc) * 8 + h) * 512 + D);
                    }
                    zs2[chf * 512 + D] = a;
                }
                __syncthreads();
                if (tid < 512) zs[tid] = (zs2[tid] + zs2[512 + tid]) * ecs[16];
                __syncthreads();
                gemv_block<16, 64, 8>(zs, A.crossW + ((size_t)(l * 4 + 2)) * 262144,
                                      512, h * 64, part);
                if (tid < 64)
                    csf(A.attnb + (size_t)b * 512 + h * 64 + tid,
                        gemv_reduce<64, 64>(part) + A.crossB[(l * 4 + 2) * 512 + h * 64 + tid]);
            }
            gsync(A.bar);

            // ---------------- S7: y2 = attnb@Wco + bco + lny1 --------------
            if (bid < 32) {
                int b = bid >> 1, ch = bid & 1;
                float* xsw = sm;
                if (tid < 512) xsw[tid] = clf(A.attnb + (size_t)b * 512 + tid);
                __syncthreads();
                gemv_block<64, 16, 32>(xsw, A.crossW + ((size_t)(l * 4 + 3)) * 262144,
                                       512, ch * 256, part);
                if (tid < 256) {
                    int col = ch * 256 + tid;
                    float acc = gemv_reduce<256, 16>(part)
                              + A.crossB[(l * 4 + 3) * 512 + col]
                              + clf(A.lny1 + (size_t)b * 512 + col);
                    csf(A.y2 + (size_t)b * 512 + col, acc);
                }
            }
            gsync(A.bar);

            // ---------------- S8: tmpb = relu(LN(y2)@W1+b1) ----------------
            if (bid < 128) {
                int b = bid >> 3, cq = bid & 7;
                float* xsw = sm;
                ln512b(A.y2 + (size_t)b * 512, A.lng + (l * 3 + 1) * 512,
                       A.lnb + (l * 3 + 1) * 512, 1, xsw, red);
                if (cq == 0 && tid < 512)
                    csf(A.lny2 + (size_t)b * 512 + tid, xsw[tid]);
                gemv_block<64, 16, 32>(xsw, A.fW1 + (size_t)l * 512 * 2048,
                                       2048, cq * 256, part);
                if (tid < 256) {
                    int col = cq * 256 + tid;
                    float acc = gemv_reduce<256, 16>(part) + A.fb1[l * 2048 + col];
                    csf(A.tmpb + (size_t)b * 2048 + col, fmaxf(acc, 0.f));
                }
            }
            gsync(A.bar);

            // ---------------- S9: y3 = tmpb@W2 + b2 + lny2 -----------------
            if (bid < 64) {
                int b = bid >> 2, cq = bid & 3;
                float* ts = sm;   // 2048
                #pragma unroll
                for (int it = 0; it < 2; it++) {
                    int p = tid + it * 1024;
                    ts[p] = clf(A.tmpb + (size_t)b * 2048 + p);
                }
                __syncthreads();
                gemv_block<32, 32, 64>(ts, A.fW2 + (size_t)l * 2048 * 512,
                                       512, cq * 128, part);
                if (tid < 128) {
                    int col = cq * 128 + tid;
                    float acc = gemv_reduce<128, 32>(part) + A.fb2[l * 512 + col]
                              + clf(A.lny2 + (size_t)b * 512 + col);
                    csf(A.y3 + (size_t)b * 512 + col, acc);
                }
            }
            gsync(A.bar);
        } // l

        // ---------------- S_out: logits for step t ----------------
        if (bid < 16) {
            int b = bid;
            float* xsw = sm;
            ln512b(A.y3 + (size_t)b * 512, A.lng + 11 * 512, A.lnb + 11 * 512, 1, xsw, red);
            gemv_block<64, 16, 32>(xsw, A.outW, 256, 0, part);
            if (tid < 256) {
                float acc = gemv_reduce<256, 16>(part) + A.outB[tid];
                csf(A.out + (size_t)b * 4096 + t * 256 + tid, acc);
            }
        }
        gsync(A.bar);
    } // t
}

// ---------------------------------------------------------------------------

extern "C" void kernel_launch(void* const* d_in, const int* in_sizes, int n_in,
                              void* d_out, int out_size, void* d_ws, size_t ws_size,
                              hipStream_t stream) {
    Args A;
    A.enc    = (const float*)d_in[0];
    A.encIn  = (const float*)d_in[1];
    A.embW   = (const float*)d_in[2];
    A.embB   = (const float*)d_in[3];
    A.outW   = (const float*)d_in[4];
    A.outB   = (const float*)d_in[5];
    A.selfW  = (const float*)d_in[6];
    A.selfB  = (const float*)d_in[7];
    A.crossW = (const float*)d_in[8];
    A.crossB = (const float*)d_in[9];
    A.fW1    = (const float*)d_in[10];
    A.fb1    = (const float*)d_in[11];
    A.fW2    = (const float*)d_in[12];
    A.fb2    = (const float*)d_in[13];
    A.lng    = (const float*)d_in[14];
    A.lnb    = (const float*)d_in[15];
    A.out    = (float*)d_out;

    char* ws = (char*)d_ws;
    size_t off = 0;
    auto alloc = [&](size_t bytes) -> char* {
        char* p = ws + off;
        off = (off + bytes + 255) & ~(size_t)255;
        return p;
    };
    char* barrier = alloc(4096);
    A.bar = (unsigned*)barrier;
    A.pos   = (float*)alloc(16 * 512 * 4);
    A.x0    = (float*)alloc(16 * 512 * 4);
    A.qbuf  = (float*)alloc(16 * 512 * 4);
    A.y1    = (float*)alloc(16 * 512 * 4);
    A.y2    = (float*)alloc(16 * 512 * 4);
    A.y3    = (float*)alloc(16 * 512 * 4);
    A.attnb = (float*)alloc(16 * 512 * 4);
    A.lny1  = (float*)alloc(16 * 512 * 4);
    A.lny2  = (float*)alloc(16 * 512 * 4);
    A.qt    = (float*)alloc((size_t)16 * 8 * 512 * 4);
    A.Pm2   = (float*)alloc(16 * 16 * 8 * 4);
    A.Ps2   = (float*)alloc(16 * 16 * 8 * 4);
    A.Pz    = (float*)alloc((size_t)16 * 16 * 8 * 512 * 4);
    A.tmpb  = (float*)alloc((size_t)16 * 2048 * 4);
    A.selfK = (float*)alloc((size_t)4 * 16 * 16 * 512 * 4);
    A.selfV = (float*)alloc((size_t)4 * 16 * 16 * 512 * 4);
    if (off > ws_size) return;   // ~9 MB — always fits

    hipMemsetAsync(barrier, 0, 4096, stream);
    k_mega<<<dim3(NB), dim3(NTHR), 0, stream>>>(A);
}

// Round 9
// 7178.724 us; speedup vs baseline: 4.1474x; 1.1343x over previous
//
#include <hip/hip_runtime.h>

// ---------------------------------------------------------------------------
// Decoder_49005576847865 — persistent decoder with INDEPENDENT BATCH GROUPS.
//   B=16, d=512, H=8 (dh=64), L=4, dff=2048, Lenc=2048, 16 steps, vocab=256.
// Round 9: batches are fully independent => replace the 256-block global
//   barrier with 16 per-batch groups of 16 blocks (group = bid>>4 = b,
//   role = bid&15). Each group runs its whole 16-step decode decoupled,
//   syncing only its own 16 blocks (fence-free relaxed protocol). enc stays
//   block-local LDS (round 8); weight slices are role-pinned (L2-stable).
// ---------------------------------------------------------------------------

typedef unsigned short ushort_t;
typedef __attribute__((ext_vector_type(4))) float f32x4;
typedef __attribute__((ext_vector_type(8))) unsigned short us8;
typedef __attribute__((ext_vector_type(4))) unsigned short us4;

#define NB 256
#define NTHR 1024

__device__ __forceinline__ float bf2f(ushort_t u) {
    union { unsigned int i; float f; } v; v.i = ((unsigned int)u) << 16; return v.f;
}
__device__ __forceinline__ ushort_t f2bf(float f) {
    union { unsigned int i; float f; } v; v.f = f;
    return (ushort_t)((v.i + 0x7FFF + ((v.i >> 16) & 1)) >> 16);   // RNE
}
__device__ __forceinline__ float wave_sum(float v) {
    #pragma unroll
    for (int m = 32; m; m >>= 1) v += __shfl_xor(v, m);
    return v;
}
__device__ __forceinline__ float wave_max(float v) {
    #pragma unroll
    for (int m = 32; m; m >>= 1) v = fmaxf(v, __shfl_xor(v, m));
    return v;
}

// ---- coherent (agent-scope, fence-free) access for mutable activations -----
union U64C { unsigned long long u; float2 f; };
__device__ __forceinline__ float clf(const float* p) {
    return __hip_atomic_load(p, __ATOMIC_RELAXED, __HIP_MEMORY_SCOPE_AGENT);
}
__device__ __forceinline__ void csf(float* p, float v) {
    __hip_atomic_store(p, v, __ATOMIC_RELAXED, __HIP_MEMORY_SCOPE_AGENT);
}
__device__ __forceinline__ float2 clf2(const float* p) {
    U64C c; c.u = __hip_atomic_load((unsigned long long*)p, __ATOMIC_RELAXED,
                                    __HIP_MEMORY_SCOPE_AGENT);
    return c.f;
}
__device__ __forceinline__ void csf2(float* p, float x, float y) {
    U64C c; c.f.x = x; c.f.y = y;
    __hip_atomic_store((unsigned long long*)p, c.u, __ATOMIC_RELAXED,
                       __HIP_MEMORY_SCOPE_AGENT);
}

// ---- fence-free PER-GROUP barrier (16 blocks, relaxed-only) -----------------
// cnt at bar[g*32] (128B apart), rel at bar[512 + g*32]. Monotonic epochs.
__device__ __forceinline__ void gbar(unsigned* bar, int g) {
    __syncthreads();
    if (threadIdx.x == 0) {
        unsigned* cnt = bar + g * 32;
        unsigned* rel = bar + 512 + g * 32;
        unsigned a = __hip_atomic_fetch_add(cnt, 1u, __ATOMIC_RELAXED,
                                            __HIP_MEMORY_SCOPE_AGENT);
        unsigned e = (a >> 4) + 1u;
        if ((a & 15u) == 15u) {
            __hip_atomic_store(rel, e, __ATOMIC_RELAXED, __HIP_MEMORY_SCOPE_AGENT);
        } else {
            while ((int)(__hip_atomic_load(rel, __ATOMIC_RELAXED,
                                           __HIP_MEMORY_SCOPE_AGENT) - e) < 0)
                __builtin_amdgcn_s_sleep(2);
        }
    }
    __syncthreads();
}

// ---- block-wide LN of one 512 row (1024 threads; first 512 carry data) -----
__device__ __forceinline__ void ln512b(const float* __restrict__ row,
                                       const float* __restrict__ g,
                                       const float* __restrict__ be,
                                       int use_ln, float* dst, float* red) {
    int tid = threadIdx.x;
    float a = (tid < 512) ? clf(row + tid) : 0.f;
    if (use_ln) {
        float s = wave_sum(a);
        if ((tid & 63) == 0) red[tid >> 6] = s;
        __syncthreads();
        float tot = 0.f;
        #pragma unroll
        for (int i = 0; i < 16; i++) tot += red[i];
        float mu = tot * (1.f / 512.f);
        float d = (tid < 512) ? (a - mu) : 0.f;
        float v = wave_sum(d * d);
        __syncthreads();
        if ((tid & 63) == 0) red[tid >> 6] = v;
        __syncthreads();
        float vt = 0.f;
        #pragma unroll
        for (int i = 0; i < 16; i++) vt += red[i];
        float rstd = rsqrtf(vt * (1.f / 512.f) + 1e-6f);
        if (tid < 512) dst[tid] = d * rstd * g[tid] + be[tid];
    } else {
        if (tid < 512) dst[tid] = a;
    }
    __syncthreads();
}

// ---- split-K GEMV: NC=NCQ*4 cols, S slices of KS rows; ends in syncthreads -
template<int NCQ, int S, int KS>
__device__ __forceinline__ void gemv_g(const float* xs, const float* __restrict__ W,
                                       int ldw, int col0, float* part) {
    int tid = threadIdx.x;
    if (tid < NCQ * S) {
        int cq = tid & (NCQ - 1);
        int ks = tid / NCQ;
        const float* Wp = W + (size_t)(ks * KS) * ldw + col0 + cq * 4;
        const float* xp = xs + ks * KS;
        f32x4 acc = {0.f, 0.f, 0.f, 0.f};
        #pragma unroll 8
        for (int r = 0; r < KS; r++) {
            f32x4 wv = *(const f32x4*)(Wp + (size_t)r * ldw);
            acc += xp[r] * wv;
        }
        *(f32x4*)(part + (ks * NCQ + cq) * 4) = acc;
    }
    __syncthreads();
}
template<int NC, int S>
__device__ __forceinline__ float gemv_r(const float* part) {
    float a = 0.f;
    #pragma unroll
    for (int s = 0; s < S; s++) a += part[s * NC + threadIdx.x];
    return a;
}

struct Args {
    const float *enc, *encIn, *embW, *embB, *outW, *outB;
    const float *selfW, *selfB, *crossW, *crossB;
    const float *fW1, *fb1, *fW2, *fb2, *lng, *lnb;
    float* out;
    unsigned* bar;
    float *x0, *qbuf, *y1, *y2, *y3, *attnb;
    float *lny1, *lny2, *qt, *Pm2, *Ps2, *Pz, *tmpb, *selfK, *selfV;
};

// ---------------------------------------------------------------------------

__global__ __launch_bounds__(NTHR, 1) void k_mega(Args A) {
    __shared__ ushort_t encL[65536];   // this block's 128-key enc slice (bf16)
    __shared__ float padL[128];        // this block's pad flags — persistent
    __shared__ float sm[6400];         // stage scratch (25.6 KB)
    const int bid = blockIdx.x, tid = threadIdx.x;
    const int b = bid >> 4, r = bid & 15;   // group = batch, role = slice/chunk
    float* red = sm + 1792;
    float* part = sm + 2048;
    unsigned* bar = A.bar;

    // ---------------- P0: enc->LDS + pad flags (block-local, no barrier) ---
    {
        const float* ep = A.enc + ((size_t)b * 2048 + r * 128) * 512;
        #pragma unroll 4
        for (int it = 0; it < 16; it++) {
            int idx = tid + it * 1024;
            float4 v = *(const float4*)(ep + (size_t)idx * 4);
            us4 o; o[0] = f2bf(v.x); o[1] = f2bf(v.y); o[2] = f2bf(v.z); o[3] = f2bf(v.w);
            *(us4*)(encL + idx * 4) = o;
        }
        int key = tid >> 3, sub = tid & 7;
        const float* p = A.encIn + ((size_t)b * 2048 + r * 128 + key) * 128 + sub * 16;
        int ok = 1;
        #pragma unroll
        for (int j = 0; j < 4; j++) {
            float4 v = *(const float4*)(p + j * 4);
            ok &= (v.x == 0.f) & (v.y == 0.f) & (v.z == 0.f) & (v.w == 0.f);
        }
        ok &= __shfl_xor(ok, 1); ok &= __shfl_xor(ok, 2); ok &= __shfl_xor(ok, 4);
        if (sub == 0) padL[key] = ok ? 1.f : 0.f;
    }
    __syncthreads();

    for (int t = 0; t < 16; t++) {
        // ---------------- S_emb: x0 slice (32 cols/role) -------------------
        {
            float* tok = sm;
            if (tid < 256)
                tok[tid] = (t == 0) ? 1.f
                         : clf(A.out + (size_t)b * 4096 + (t - 1) * 256 + tid);
            __syncthreads();
            gemv_g<8, 16, 16>(tok, A.embW, 512, r * 32, part);
            if (tid < 32) {
                float acc = gemv_r<32, 16>(part);
                int col = r * 32 + tid;
                float expo = (2.0f * (float)(col >> 1)) * (1.f / 512.f);
                float ang = (float)t * powf(10000.0f, -expo);
                float pv = (col & 1) ? cosf(ang) : sinf(ang);
                csf(A.x0 + (size_t)b * 512 + col,
                    (acc + A.embB[col]) * 22.627416997969522f + pv);
            }
        }
        gbar(bar, b);

        for (int l = 0; l < 4; l++) {
            const float* src = (l == 0) ? A.x0 : A.y3;
            const float* gP = (l == 0) ? nullptr : A.lng + ((l - 1) * 3 + 2) * 512;
            const float* bP = (l == 0) ? nullptr : A.lnb + ((l - 1) * 3 + 2) * 512;
            int ulnP = (l != 0);

            // ------------ S1: q/k/v fused (3 x 32 cols per role) -----------
            {
                float* xs = sm;
                ln512b(src + (size_t)b * 512, gP, bP, ulnP, xs, red);
                if (tid < 384) {
                    int m = tid >> 7, sub = tid & 127;
                    int cq = sub & 7, ks = sub >> 3;           // 16 slices of 32
                    const float* Wp = A.selfW + ((size_t)(l * 4 + m)) * 262144
                                    + (size_t)(ks * 32) * 512 + r * 32 + cq * 4;
                    const float* xp = xs + ks * 32;
                    f32x4 acc = {0.f, 0.f, 0.f, 0.f};
                    #pragma unroll 8
                    for (int rr = 0; rr < 32; rr++)
                        acc += xp[rr] * *(const f32x4*)(Wp + (size_t)rr * 512);
                    *(f32x4*)(part + m * 512 + (ks * 8 + cq) * 4) = acc;
                }
                __syncthreads();
                if (tid < 96) {
                    int m = tid >> 5, j = tid & 31;
                    float a = 0.f;
                    #pragma unroll
                    for (int s = 0; s < 16; s++) a += part[m * 512 + s * 32 + j];
                    int col = r * 32 + j;
                    a += A.selfB[(l * 4 + m) * 512 + col];
                    if (m == 0) csf(A.qbuf + (size_t)b * 512 + col, a);
                    else if (m == 1)
                        csf(A.selfK + (((size_t)l * 16 + b) * 16 + t) * 512 + col, a);
                    else
                        csf(A.selfV + (((size_t)l * 16 + b) * 16 + t) * 512 + col, a);
                }
            }
            gbar(bar, b);

            // ------------ S2: self-attn (redundant) + Wo slice + residual --
            {
                float* xr = sm; float* qs = sm + 512; float* as_ = sm + 1024;
                float* lg = sm + 1536;   // [8][16]
                ln512b(src + (size_t)b * 512, gP, bP, ulnP, xr, red);
                if (tid < 512) qs[tid] = clf(A.qbuf + (size_t)b * 512 + tid);
                __syncthreads();
                const float* Kb = A.selfK + ((size_t)l * 16 + b) * 16 * 512;
                const float* Vb = A.selfV + ((size_t)l * 16 + b) * 16 * 512;
                if (tid < 512) {
                    int idx = tid >> 2, q4 = tid & 3;
                    int h = idx >> 4, j = idx & 15;
                    if (j <= t) {
                        const float* kp = Kb + (size_t)j * 512 + h * 64 + q4 * 16;
                        const float* qp = qs + h * 64 + q4 * 16;
                        float s = 0.f;
                        #pragma unroll
                        for (int d = 0; d < 16; d += 2) {
                            float2 kv = clf2(kp + d);
                            s += qp[d] * kv.x + qp[d + 1] * kv.y;
                        }
                        s += __shfl_xor(s, 1);
                        s += __shfl_xor(s, 2);
                        if (q4 == 0) lg[h * 16 + j] = s * 0.125f;
                    }
                }
                __syncthreads();
                if (tid < 8) {
                    float m = -1e30f;
                    for (int j = 0; j <= t; j++) m = fmaxf(m, lg[tid * 16 + j]);
                    float ssum = 0.f;
                    for (int j = 0; j <= t; j++) {
                        float e = __expf(lg[tid * 16 + j] - m);
                        lg[tid * 16 + j] = e; ssum += e;
                    }
                    float inv = 1.f / ssum;
                    for (int j = 0; j <= t; j++) lg[tid * 16 + j] *= inv;
                }
                __syncthreads();
                if (tid < 512) {
                    int h = tid >> 6;
                    float a = 0.f;
                    for (int j = 0; j <= t; j++)
                        a += lg[h * 16 + j] * clf(Vb + (size_t)j * 512 + tid);
                    as_[tid] = a;
                }
                __syncthreads();
                gemv_g<8, 32, 16>(as_, A.selfW + ((size_t)(l * 4 + 3)) * 262144,
                                  512, r * 32, part);
                if (tid < 32) {
                    float acc = gemv_r<32, 32>(part);
                    int col = r * 32 + tid;
                    csf(A.y1 + (size_t)b * 512 + col,
                        acc + A.selfB[(l * 4 + 3) * 512 + col] + xr[col]);
                }
            }
            gbar(bar, b);

            // ------------ S34: qc_h (redundant per half) + qt_h half -------
            {
                int h = r >> 1, half = r & 1;
                float* xsw = sm; float* qch = sm + 1024;
                ln512b(A.y1 + (size_t)b * 512, A.lng + (l * 3) * 512,
                       A.lnb + (l * 3) * 512, 1, xsw, red);
                if (r == 0 && tid < 512)
                    csf(A.lny1 + (size_t)b * 512 + tid, xsw[tid]);
                gemv_g<16, 32, 16>(xsw, A.crossW + ((size_t)(l * 4)) * 262144,
                                   512, h * 64, part);
                if (tid < 64)
                    qch[tid] = gemv_r<64, 32>(part)
                             + A.crossB[(l * 4) * 512 + h * 64 + tid];
                __syncthreads();
                {
                    int D = half * 256 + (tid >> 2), q4 = tid & 3;
                    const float* wr = A.crossW + ((size_t)(l * 4 + 1)) * 262144
                                    + (size_t)D * 512 + h * 64 + q4 * 16;
                    const float* qp = qch + q4 * 16;
                    float a = 0.f;
                    #pragma unroll
                    for (int j = 0; j < 16; j += 4) {
                        f32x4 wv = *(const f32x4*)(wr + j);
                        a += qp[j]*wv[0] + qp[j+1]*wv[1] + qp[j+2]*wv[2] + qp[j+3]*wv[3];
                    }
                    a += __shfl_xor(a, 1);
                    a += __shfl_xor(a, 2);
                    if (q4 == 0)
                        csf(A.qt + ((size_t)b * 8 + h) * 512 + D, a * 0.125f);
                }
            }
            gbar(bar, b);

            // ------------ S5: flash cross-attn from LDS (role = chunk) -----
            {
                float* qts = sm;            // [8][520]
                float* lge = sm + 4160;     // [8][128]
                float* wms = sm + 5184;     // [16]
                float* wss = sm + 5200;     // [16]
                #pragma unroll
                for (int it = 0; it < 4; it++) {
                    int idx = tid + it * 1024;
                    qts[(idx >> 9) * 520 + (idx & 511)] =
                        clf(A.qt + (size_t)b * 4096 + idx);
                }
                __syncthreads();
                #pragma unroll
                for (int it = 0; it < 4; it++) {
                    int key = it * 32 + (tid >> 5);
                    int hh = (tid >> 2) & 7, pq = tid & 3;
                    const ushort_t* er = encL + key * 512;
                    const float* q = qts + hh * 520;
                    float a0 = 0.f, a1 = 0.f;
                    #pragma unroll
                    for (int ch = 0; ch < 16; ch++) {
                        int c8 = (pq + ch * 4) * 8;
                        us8 ev8 = *(const us8*)(er + c8);
                        const float* qp = q + c8;
                        a0 += bf2f(ev8[0])*qp[0] + bf2f(ev8[1])*qp[1]
                            + bf2f(ev8[2])*qp[2] + bf2f(ev8[3])*qp[3];
                        a1 += bf2f(ev8[4])*qp[4] + bf2f(ev8[5])*qp[5]
                            + bf2f(ev8[6])*qp[6] + bf2f(ev8[7])*qp[7];
                    }
                    float acc = a0 + a1;
                    acc += __shfl_xor(acc, 1);
                    acc += __shfl_xor(acc, 2);
                    if (pq == 0)
                        lge[hh * 128 + key] = (padL[key] != 0.f) ? -2e30f : acc;
                }
                __syncthreads();
                {   // softmax over this chunk's 128 keys (wave = half a head)
                    int hh = tid >> 7, k = tid & 127;
                    float lv = lge[hh * 128 + k];
                    float mv = wave_max(lv);
                    if ((tid & 63) == 0) wms[tid >> 6] = mv;
                    __syncthreads();
                    float m = fmaxf(wms[hh * 2], wms[hh * 2 + 1]);
                    float ev = __expf(lv - m);
                    float sv = wave_sum(ev);
                    if ((tid & 63) == 0) wss[tid >> 6] = sv;
                    lge[hh * 128 + k] = ev;
                    __syncthreads();
                    if (tid < 8) {
                        int bc = b * 16 + r;
                        csf(A.Pm2 + bc * 8 + tid, fmaxf(wms[tid * 2], wms[tid * 2 + 1]));
                        csf(A.Ps2 + bc * 8 + tid, wss[tid * 2] + wss[tid * 2 + 1]);
                    }
                }
                __syncthreads();
                {   // z = sum_k ev * enc_k (LDS)
                    int hz = tid >> 7, ii = tid & 127;
                    f32x4 z = {0.f, 0.f, 0.f, 0.f};
                    const ushort_t* ep2 = encL + ii * 4;
                    const float* le = lge + hz * 128;
                    #pragma unroll 4
                    for (int k = 0; k < 128; k++) {
                        float ev = le[k];
                        us4 e4 = *(const us4*)(ep2 + k * 512);
                        z[0] += ev * bf2f(e4[0]); z[1] += ev * bf2f(e4[1]);
                        z[2] += ev * bf2f(e4[2]); z[3] += ev * bf2f(e4[3]);
                    }
                    float* dst = A.Pz + ((size_t)((b * 16 + r) * 8 + hz)) * 512 + ii * 4;
                    csf2(dst, z[0], z[1]);
                    csf2(dst + 2, z[2], z[3]);
                }
            }
            gbar(bar, b);

            // ------------ S6: combine chunks + Wv slice --------------------
            {
                int h = r >> 1, half = r & 1;
                float* zs = sm;           // 512
                float* ecs = sm + 1600;   // 17
                if (tid < 16) {
                    float mcv = clf(A.Pm2 + (b * 16 + tid) * 8 + h);
                    float mm = mcv;
                    mm = fmaxf(mm, __shfl_xor(mm, 1));
                    mm = fmaxf(mm, __shfl_xor(mm, 2));
                    mm = fmaxf(mm, __shfl_xor(mm, 4));
                    mm = fmaxf(mm, __shfl_xor(mm, 8));
                    float ec = __expf(mcv - mm);
                    float sv = ec * clf(A.Ps2 + (b * 16 + tid) * 8 + h);
                    sv += __shfl_xor(sv, 1); sv += __shfl_xor(sv, 2);
                    sv += __shfl_xor(sv, 4); sv += __shfl_xor(sv, 8);
                    ecs[tid] = ec;
                    if (tid == 0) ecs[16] = 1.f / sv;
                }
                __syncthreads();
                if (tid < 512) {
                    float a = 0.f;
                    #pragma unroll
                    for (int cc = 0; cc < 16; cc++)
                        a += ecs[cc] * clf(A.Pz + ((size_t)(b * 16 + cc) * 8 + h) * 512 + tid);
                    zs[tid] = a * ecs[16];
                }
                __syncthreads();
                gemv_g<8, 32, 16>(zs, A.crossW + ((size_t)(l * 4 + 2)) * 262144,
                                  512, h * 64 + half * 32, part);
                if (tid < 32) {
                    int col = h * 64 + half * 32 + tid;
                    csf(A.attnb + (size_t)b * 512 + col,
                        gemv_r<32, 32>(part) + A.crossB[(l * 4 + 2) * 512 + col]);
                }
            }
            gbar(bar, b);

            // ------------ S7: y2 slice = attnb@Wco + bco + lny1 ------------
            {
                float* xa = sm;
                if (tid < 512) xa[tid] = clf(A.attnb + (size_t)b * 512 + tid);
                __syncthreads();
                gemv_g<8, 32, 16>(xa, A.crossW + ((size_t)(l * 4 + 3)) * 262144,
                                  512, r * 32, part);
                if (tid < 32) {
                    int col = r * 32 + tid;
                    csf(A.y2 + (size_t)b * 512 + col,
                        gemv_r<32, 32>(part) + A.crossB[(l * 4 + 3) * 512 + col]
                        + clf(A.lny1 + (size_t)b * 512 + col));
                }
            }
            gbar(bar, b);

            // ------------ S8: tmpb slice (128 cols) = relu(LN(y2)@W1) ------
            {
                float* xsw = sm;
                ln512b(A.y2 + (size_t)b * 512, A.lng + (l * 3 + 1) * 512,
                       A.lnb + (l * 3 + 1) * 512, 1, xsw, red);
                if (r == 0 && tid < 512)
                    csf(A.lny2 + (size_t)b * 512 + tid, xsw[tid]);
                gemv_g<32, 32, 16>(xsw, A.fW1 + (size_t)l * 512 * 2048,
                                   2048, r * 128, part);
                if (tid < 128) {
                    int col = r * 128 + tid;
                    csf(A.tmpb + (size_t)b * 2048 + col,
                        fmaxf(gemv_r<128, 32>(part) + A.fb1[l * 2048 + col], 0.f));
                }
            }
            gbar(bar, b);

            // ------------ S9: y3 slice = tmpb@W2 + b2 + lny2 ---------------
            {
                float* ts = sm;   // 2048
                ts[tid] = clf(A.tmpb + (size_t)b * 2048 + tid);
                ts[tid + 1024] = clf(A.tmpb + (size_t)b * 2048 + tid + 1024);
                __syncthreads();
                gemv_g<8, 32, 64>(ts, A.fW2 + (size_t)l * 2048 * 512,
                                  512, r * 32, part);
                if (tid < 32) {
                    int col = r * 32 + tid;
                    csf(A.y3 + (size_t)b * 512 + col,
                        gemv_r<32, 32>(part) + A.fb2[l * 512 + col]
                        + clf(A.lny2 + (size_t)b * 512 + col));
                }
            }
            gbar(bar, b);
        } // l

        // ---------------- S_out: logits slice (16 cols/role) ---------------
        {
            float* xsw = sm;
            ln512b(A.y3 + (size_t)b * 512, A.lng + 11 * 512, A.lnb + 11 * 512,
                   1, xsw, red);
            gemv_g<4, 32, 16>(xsw, A.outW, 256, r * 16, part);
            if (tid < 16) {
                int col = r * 16 + tid;
                csf(A.out + (size_t)b * 4096 + t * 256 + col,
                    gemv_r<16, 32>(part) + A.outB[col]);
            }
        }
        gbar(bar, b);
    } // t
}

// ---------------------------------------------------------------------------

extern "C" void kernel_launch(void* const* d_in, const int* in_sizes, int n_in,
                              void* d_out, int out_size, void* d_ws, size_t ws_size,
                              hipStream_t stream) {
    Args A;
    A.enc    = (const float*)d_in[0];
    A.encIn  = (const float*)d_in[1];
    A.embW   = (const float*)d_in[2];
    A.embB   = (const float*)d_in[3];
    A.outW   = (const float*)d_in[4];
    A.outB   = (const float*)d_in[5];
    A.selfW  = (const float*)d_in[6];
    A.selfB  = (const float*)d_in[7];
    A.crossW = (const float*)d_in[8];
    A.crossB = (const float*)d_in[9];
    A.fW1    = (const float*)d_in[10];
    A.fb1    = (const float*)d_in[11];
    A.fW2    = (const float*)d_in[12];
    A.fb2    = (const float*)d_in[13];
    A.lng    = (const float*)d_in[14];
    A.lnb    = (const float*)d_in[15];
    A.out    = (float*)d_out;

    char* ws = (char*)d_ws;
    size_t off = 0;
    auto alloc = [&](size_t bytes) -> char* {
        char* p = ws + off;
        off = (off + bytes + 255) & ~(size_t)255;
        return p;
    };
    char* barrier = alloc(4096);
    A.bar = (unsigned*)barrier;
    A.x0    = (float*)alloc(16 * 512 * 4);
    A.qbuf  = (float*)alloc(16 * 512 * 4);
    A.y1    = (float*)alloc(16 * 512 * 4);
    A.y2    = (float*)alloc(16 * 512 * 4);
    A.y3    = (float*)alloc(16 * 512 * 4);
    A.attnb = (float*)alloc(16 * 512 * 4);
    A.lny1  = (float*)alloc(16 * 512 * 4);
    A.lny2  = (float*)alloc(16 * 512 * 4);
    A.qt    = (float*)alloc((size_t)16 * 8 * 512 * 4);
    A.Pm2   = (float*)alloc(16 * 16 * 8 * 4);
    A.Ps2   = (float*)alloc(16 * 16 * 8 * 4);
    A.Pz    = (float*)alloc((size_t)16 * 16 * 8 * 512 * 4);
    A.tmpb  = (float*)alloc((size_t)16 * 2048 * 4);
    A.selfK = (float*)alloc((size_t)4 * 16 * 16 * 512 * 4);
    A.selfV = (float*)alloc((size_t)4 * 16 * 16 * 512 * 4);
    if (off > ws_size) return;   // ~9 MB — always fits

    hipMemsetAsync(barrier, 0, 4096, stream);
    k_mega<<<dim3(NB), dim3(NTHR), 0, stream>>>(A);
}

// Round 10
// 5116.297 us; speedup vs baseline: 5.8193x; 1.4031x over previous
//
#include <hip/hip_runtime.h>

// ---------------------------------------------------------------------------
// Decoder_49005576847865 — persistent decoder, independent batch groups.
//   B=16, d=512, H=8 (dh=64), L=4, dff=2048, Lenc=2048, 16 steps, vocab=256.
// Round 10: round-9 structure (groups of 16 blocks, per-group fence-free
//   barrier, enc LDS-resident) + memory-level-parallelism rewrite:
//   * gemv_all: ALL 1024 threads, 2-16 unrolled f32x4 loads/thread,
//     in-wave shfl reduce + single 16-way LDS reduce.
//   * S1 fused q/k/v triple-accumulator GEMV.
//   * all coherent staging packed as 64-bit (clf2); S2 AV on 1024 threads.
// ---------------------------------------------------------------------------

typedef unsigned short ushort_t;
typedef __attribute__((ext_vector_type(4))) float f32x4;
typedef __attribute__((ext_vector_type(8))) unsigned short us8;
typedef __attribute__((ext_vector_type(4))) unsigned short us4;

#define NB 256
#define NTHR 1024

__device__ __forceinline__ float bf2f(ushort_t u) {
    union { unsigned int i; float f; } v; v.i = ((unsigned int)u) << 16; return v.f;
}
__device__ __forceinline__ ushort_t f2bf(float f) {
    union { unsigned int i; float f; } v; v.f = f;
    return (ushort_t)((v.i + 0x7FFF + ((v.i >> 16) & 1)) >> 16);   // RNE
}
__device__ __forceinline__ float wave_sum(float v) {
    #pragma unroll
    for (int m = 32; m; m >>= 1) v += __shfl_xor(v, m);
    return v;
}
__device__ __forceinline__ float wave_max(float v) {
    #pragma unroll
    for (int m = 32; m; m >>= 1) v = fmaxf(v, __shfl_xor(v, m));
    return v;
}

// ---- coherent (agent-scope, fence-free) access for mutable activations -----
union U64C { unsigned long long u; float2 f; };
__device__ __forceinline__ float clf(const float* p) {
    return __hip_atomic_load(p, __ATOMIC_RELAXED, __HIP_MEMORY_SCOPE_AGENT);
}
__device__ __forceinline__ void csf(float* p, float v) {
    __hip_atomic_store(p, v, __ATOMIC_RELAXED, __HIP_MEMORY_SCOPE_AGENT);
}
__device__ __forceinline__ float2 clf2(const float* p) {
    U64C c; c.u = __hip_atomic_load((unsigned long long*)p, __ATOMIC_RELAXED,
                                    __HIP_MEMORY_SCOPE_AGENT);
    return c.f;
}
__device__ __forceinline__ void csf2(float* p, float x, float y) {
    U64C c; c.f.x = x; c.f.y = y;
    __hip_atomic_store((unsigned long long*)p, c.u, __ATOMIC_RELAXED,
                       __HIP_MEMORY_SCOPE_AGENT);
}

// ---- fence-free PER-GROUP barrier (16 blocks, relaxed-only) -----------------
__device__ __forceinline__ void gbar(unsigned* bar, int g) {
    __syncthreads();
    if (threadIdx.x == 0) {
        unsigned* cnt = bar + g * 32;
        unsigned* rel = bar + 512 + g * 32;
        unsigned a = __hip_atomic_fetch_add(cnt, 1u, __ATOMIC_RELAXED,
                                            __HIP_MEMORY_SCOPE_AGENT);
        unsigned e = (a >> 4) + 1u;
        if ((a & 15u) == 15u) {
            __hip_atomic_store(rel, e, __ATOMIC_RELAXED, __HIP_MEMORY_SCOPE_AGENT);
        } else {
            while ((int)(__hip_atomic_load(rel, __ATOMIC_RELAXED,
                                           __HIP_MEMORY_SCOPE_AGENT) - e) < 0)
                __builtin_amdgcn_s_sleep(2);
        }
    }
    __syncthreads();
}

// ---- block-wide LN of one 512 row (1024 threads; first 512 carry data) -----
__device__ __forceinline__ void ln512b(const float* __restrict__ row,
                                       const float* __restrict__ g,
                                       const float* __restrict__ be,
                                       int use_ln, float* dst, float* red) {
    int tid = threadIdx.x;
    float a = (tid < 512) ? clf(row + tid) : 0.f;
    if (use_ln) {
        float s = wave_sum(a);
        if ((tid & 63) == 0) red[tid >> 6] = s;
        __syncthreads();
        float tot = 0.f;
        #pragma unroll
        for (int i = 0; i < 16; i++) tot += red[i];
        float mu = tot * (1.f / 512.f);
        float d = (tid < 512) ? (a - mu) : 0.f;
        float v = wave_sum(d * d);
        __syncthreads();
        if ((tid & 63) == 0) red[tid >> 6] = v;
        __syncthreads();
        float vt = 0.f;
        #pragma unroll
        for (int i = 0; i < 16; i++) vt += red[i];
        float rstd = rsqrtf(vt * (1.f / 512.f) + 1e-6f);
        if (tid < 512) dst[tid] = d * rstd * g[tid] + be[tid];
    } else {
        if (tid < 512) dst[tid] = a;
    }
    __syncthreads();
}

// ---- all-thread split-K GEMV: NC=NCQ*4 cols, in-wave shfl reduce -----------
// thread = (cq: col-quad, ks: k-slice). After call, col j sum = over 16 waves
// of part[w*NCQ*4 + j]. Ends in __syncthreads().
template<int NCQ, int K>
__device__ __forceinline__ void gemv_all(const float* xs, const float* __restrict__ W,
                                         int ldw, int col0, float* part) {
    constexpr int S = 1024 / NCQ;
    constexpr int KS = K / S;
    int tid = threadIdx.x;
    int cq = tid & (NCQ - 1), ks = tid / NCQ;
    const float* Wp = W + (size_t)(ks * KS) * ldw + col0 + cq * 4;
    const float* xp = xs + ks * KS;
    f32x4 acc = {0.f, 0.f, 0.f, 0.f};
    #pragma unroll
    for (int r = 0; r < KS; r++)
        acc += xp[r] * *(const f32x4*)(Wp + (size_t)r * ldw);
    #pragma unroll
    for (int m = NCQ; m < 64; m <<= 1) {
        acc[0] += __shfl_xor(acc[0], m);
        acc[1] += __shfl_xor(acc[1], m);
        acc[2] += __shfl_xor(acc[2], m);
        acc[3] += __shfl_xor(acc[3], m);
    }
    int wave = tid >> 6, lane = tid & 63;
    if (lane < NCQ) *(f32x4*)(part + (wave * NCQ + lane) * 4) = acc;
    __syncthreads();
}
template<int NCQ>
__device__ __forceinline__ float gemv_allr(const float* part) {
    float a = 0.f;
    #pragma unroll
    for (int w = 0; w < 16; w++) a += part[w * NCQ * 4 + threadIdx.x];
    return a;
}

struct Args {
    const float *enc, *encIn, *embW, *embB, *outW, *outB;
    const float *selfW, *selfB, *crossW, *crossB;
    const float *fW1, *fb1, *fW2, *fb2, *lng, *lnb;
    float* out;
    unsigned* bar;
    float *x0, *qbuf, *y1, *y2, *y3, *attnb;
    float *lny1, *lny2, *qt, *Pm2, *Ps2, *Pz, *tmpb, *selfK, *selfV;
};

// ---------------------------------------------------------------------------

__global__ __launch_bounds__(NTHR, 1) void k_mega(Args A) {
    __shared__ ushort_t encL[65536];   // this block's 128-key enc slice (bf16)
    __shared__ float padL[128];        // this block's pad flags — persistent
    __shared__ float sm[6400];         // stage scratch (25.6 KB)
    const int bid = blockIdx.x, tid = threadIdx.x;
    const int b = bid >> 4, r = bid & 15;   // group = batch, role = slice/chunk
    unsigned* bar = A.bar;

    // ---------------- P0: enc->LDS + pad flags (block-local) ---------------
    {
        const float* ep = A.enc + ((size_t)b * 2048 + r * 128) * 512;
        #pragma unroll 4
        for (int it = 0; it < 16; it++) {
            int idx = tid + it * 1024;
            float4 v = *(const float4*)(ep + (size_t)idx * 4);
            us4 o; o[0] = f2bf(v.x); o[1] = f2bf(v.y); o[2] = f2bf(v.z); o[3] = f2bf(v.w);
            *(us4*)(encL + idx * 4) = o;
        }
        int key = tid >> 3, sub = tid & 7;
        const float* p = A.encIn + ((size_t)b * 2048 + r * 128 + key) * 128 + sub * 16;
        int ok = 1;
        #pragma unroll
        for (int j = 0; j < 4; j++) {
            float4 v = *(const float4*)(p + j * 4);
            ok &= (v.x == 0.f) & (v.y == 0.f) & (v.z == 0.f) & (v.w == 0.f);
        }
        ok &= __shfl_xor(ok, 1); ok &= __shfl_xor(ok, 2); ok &= __shfl_xor(ok, 4);
        if (sub == 0) padL[key] = ok ? 1.f : 0.f;
    }
    __syncthreads();

    for (int t = 0; t < 16; t++) {
        // ---------------- S_emb: x0 slice (32 cols/role) -------------------
        {
            float* tok = sm;            // 256
            float* part = sm + 256;     // 512
            if (tid < 256)
                tok[tid] = (t == 0) ? 1.f
                         : clf(A.out + (size_t)b * 4096 + (t - 1) * 256 + tid);
            __syncthreads();
            gemv_all<8, 256>(tok, A.embW, 512, r * 32, part);
            if (tid < 32) {
                float acc = gemv_allr<8>(part);
                int col = r * 32 + tid;
                float expo = (2.0f * (float)(col >> 1)) * (1.f / 512.f);
                float ang = (float)t * powf(10000.0f, -expo);
                float pv = (col & 1) ? cosf(ang) : sinf(ang);
                csf(A.x0 + (size_t)b * 512 + col,
                    (acc + A.embB[col]) * 22.627416997969522f + pv);
            }
        }
        gbar(bar, b);

        for (int l = 0; l < 4; l++) {
            const float* src = (l == 0) ? A.x0 : A.y3;
            const float* gP = (l == 0) ? nullptr : A.lng + ((l - 1) * 3 + 2) * 512;
            const float* bP = (l == 0) ? nullptr : A.lnb + ((l - 1) * 3 + 2) * 512;
            int ulnP = (l != 0);

            // ------------ S1: q/k/v fused triple GEMV (32 cols each) -------
            {
                float* xs = sm;            // 512
                float* red = sm + 512;     // 16
                float* part = sm + 1024;   // 3*512
                ln512b(src + (size_t)b * 512, gP, bP, ulnP, xs, red);
                int cq = tid & 7, ks = tid >> 3;         // 128 slices of 4
                const float* xp = xs + ks * 4;
                f32x4 a0 = {0.f,0.f,0.f,0.f}, a1 = a0, a2 = a0;
                const float* W0 = A.selfW + ((size_t)(l * 4 + 0)) * 262144
                                + (size_t)(ks * 4) * 512 + r * 32 + cq * 4;
                const float* W1 = W0 + 262144;
                const float* W2 = W1 + 262144;
                #pragma unroll
                for (int rr = 0; rr < 4; rr++) {
                    float x = xp[rr];
                    a0 += x * *(const f32x4*)(W0 + (size_t)rr * 512);
                    a1 += x * *(const f32x4*)(W1 + (size_t)rr * 512);
                    a2 += x * *(const f32x4*)(W2 + (size_t)rr * 512);
                }
                #pragma unroll
                for (int m = 8; m < 64; m <<= 1) {
                    #pragma unroll
                    for (int j = 0; j < 4; j++) {
                        a0[j] += __shfl_xor(a0[j], m);
                        a1[j] += __shfl_xor(a1[j], m);
                        a2[j] += __shfl_xor(a2[j], m);
                    }
                }
                int wave = tid >> 6, lane = tid & 63;
                if (lane < 8) {
                    *(f32x4*)(part + (wave * 8 + lane) * 4) = a0;
                    *(f32x4*)(part + 512 + (wave * 8 + lane) * 4) = a1;
                    *(f32x4*)(part + 1024 + (wave * 8 + lane) * 4) = a2;
                }
                __syncthreads();
                if (tid < 96) {
                    int m = tid >> 5, j = tid & 31;
                    float a = 0.f;
                    #pragma unroll
                    for (int w = 0; w < 16; w++) a += part[m * 512 + w * 32 + j];
                    int col = r * 32 + j;
                    a += A.selfB[(l * 4 + m) * 512 + col];
                    if (m == 0) csf(A.qbuf + (size_t)b * 512 + col, a);
                    else if (m == 1)
                        csf(A.selfK + (((size_t)l * 16 + b) * 16 + t) * 512 + col, a);
                    else
                        csf(A.selfV + (((size_t)l * 16 + b) * 16 + t) * 512 + col, a);
                }
            }
            gbar(bar, b);

            // ------------ S2: self-attn + Wo slice + residual --------------
            {
                float* xr = sm;            // 512
                float* qs = sm + 512;      // 512 (later reused for AV result)
                float* as2 = sm + 1024;    // 1024
                float* lg = sm + 2048;     // 128
                float* red = sm + 2176;    // 16
                float* part = sm + 2560;   // 512
                ln512b(src + (size_t)b * 512, gP, bP, ulnP, xr, red);
                if (tid < 256) {
                    float2 v = clf2(A.qbuf + (size_t)b * 512 + tid * 2);
                    qs[tid * 2] = v.x; qs[tid * 2 + 1] = v.y;
                }
                __syncthreads();
                const float* Kb = A.selfK + ((size_t)l * 16 + b) * 16 * 512;
                const float* Vb = A.selfV + ((size_t)l * 16 + b) * 16 * 512;
                if (tid < 512) {
                    int idx = tid >> 2, q4 = tid & 3;
                    int h = idx >> 4, j = idx & 15;
                    if (j <= t) {
                        const float* kp = Kb + (size_t)j * 512 + h * 64 + q4 * 16;
                        const float* qp = qs + h * 64 + q4 * 16;
                        float s = 0.f;
                        #pragma unroll
                        for (int d = 0; d < 16; d += 2) {
                            float2 kv = clf2(kp + d);
                            s += qp[d] * kv.x + qp[d + 1] * kv.y;
                        }
                        s += __shfl_xor(s, 1);
                        s += __shfl_xor(s, 2);
                        if (q4 == 0) lg[h * 16 + j] = s * 0.125f;
                    }
                }
                __syncthreads();
                if (tid < 8) {
                    float m = -1e30f;
                    for (int j = 0; j <= t; j++) m = fmaxf(m, lg[tid * 16 + j]);
                    float ssum = 0.f;
                    for (int j = 0; j <= t; j++) {
                        float e = __expf(lg[tid * 16 + j] - m);
                        lg[tid * 16 + j] = e; ssum += e;
                    }
                    float inv = 1.f / ssum;
                    for (int j = 0; j <= t; j++) lg[tid * 16 + j] *= inv;
                }
                __syncthreads();
                {   // AV on all 1024 threads (j parity split)
                    int col = tid & 511, jh = tid >> 9;
                    float a = 0.f;
                    for (int j = jh; j <= t; j += 2)
                        a += lg[(col >> 6) * 16 + j] * clf(Vb + (size_t)j * 512 + col);
                    as2[jh * 512 + col] = a;
                }
                __syncthreads();
                if (tid < 512) qs[tid] = as2[tid] + as2[512 + tid];
                __syncthreads();
                gemv_all<8, 512>(qs, A.selfW + ((size_t)(l * 4 + 3)) * 262144,
                                 512, r * 32, part);
                if (tid < 32) {
                    int col = r * 32 + tid;
                    csf(A.y1 + (size_t)b * 512 + col,
                        gemv_allr<8>(part) + A.selfB[(l * 4 + 3) * 512 + col] + xr[col]);
                }
            }
            gbar(bar, b);

            // ------------ S34: qc_h (redundant per half) + qt_h half -------
            {
                int h = r >> 1, half = r & 1;
                float* xsw = sm;           // 512
                float* red = sm + 512;     // 16
                float* qch = sm + 544;     // 64
                float* part = sm + 1024;   // 1024 (NCQ=16)
                ln512b(A.y1 + (size_t)b * 512, A.lng + (l * 3) * 512,
                       A.lnb + (l * 3) * 512, 1, xsw, red);
                if (r == 0 && tid < 512)
                    csf(A.lny1 + (size_t)b * 512 + tid, xsw[tid]);
                gemv_all<16, 512>(xsw, A.crossW + ((size_t)(l * 4)) * 262144,
                                  512, h * 64, part);
                if (tid < 64)
                    qch[tid] = gemv_allr<16>(part)
                             + A.crossB[(l * 4) * 512 + h * 64 + tid];
                __syncthreads();
                {   // qt[b,h,D-half] = 0.125 * qch . Wk[D][h*64..]
                    int D = half * 256 + (tid >> 2), q4 = tid & 3;
                    const float* wr = A.crossW + ((size_t)(l * 4 + 1)) * 262144
                                    + (size_t)D * 512 + h * 64 + q4 * 16;
                    const float* qp = qch + q4 * 16;
                    float a = 0.f;
                    #pragma unroll
                    for (int j = 0; j < 16; j += 4) {
                        f32x4 wv = *(const f32x4*)(wr + j);
                        a += qp[j]*wv[0] + qp[j+1]*wv[1] + qp[j+2]*wv[2] + qp[j+3]*wv[3];
                    }
                    a += __shfl_xor(a, 1);
                    a += __shfl_xor(a, 2);
                    if (q4 == 0)
                        csf(A.qt + ((size_t)b * 8 + h) * 512 + D, a * 0.125f);
                }
            }
            gbar(bar, b);

            // ------------ S5: flash cross-attn from LDS (role = chunk) -----
            {
                float* qts = sm;            // [8][520]
                float* lge = sm + 4160;     // [8][128]
                float* wms = sm + 5184;     // [16]
                float* wss = sm + 5200;     // [16]
                #pragma unroll
                for (int it = 0; it < 2; it++) {
                    int p = (tid + it * 1024) * 2;
                    float2 v = clf2(A.qt + (size_t)b * 4096 + p);
                    int row = p >> 9, d = p & 511;
                    qts[row * 520 + d] = v.x;
                    qts[row * 520 + d + 1] = v.y;
                }
                __syncthreads();
                #pragma unroll
                for (int it = 0; it < 4; it++) {
                    int key = it * 32 + (tid >> 5);
                    int hh = (tid >> 2) & 7, pq = tid & 3;
                    const ushort_t* er = encL + key * 512;
                    const float* q = qts + hh * 520;
                    float a0 = 0.f, a1 = 0.f;
                    #pragma unroll
                    for (int ch = 0; ch < 16; ch++) {
                        int c8 = (pq + ch * 4) * 8;
                        us8 ev8 = *(const us8*)(er + c8);
                        const float* qp = q + c8;
                        a0 += bf2f(ev8[0])*qp[0] + bf2f(ev8[1])*qp[1]
                            + bf2f(ev8[2])*qp[2] + bf2f(ev8[3])*qp[3];
                        a1 += bf2f(ev8[4])*qp[4] + bf2f(ev8[5])*qp[5]
                            + bf2f(ev8[6])*qp[6] + bf2f(ev8[7])*qp[7];
                    }
                    float acc = a0 + a1;
                    acc += __shfl_xor(acc, 1);
                    acc += __shfl_xor(acc, 2);
                    if (pq == 0)
                        lge[hh * 128 + key] = (padL[key] != 0.f) ? -2e30f : acc;
                }
                __syncthreads();
                {   // softmax over this chunk's 128 keys (wave = half a head)
                    int hh = tid >> 7, k = tid & 127;
                    float lv = lge[hh * 128 + k];
                    float mv = wave_max(lv);
                    if ((tid & 63) == 0) wms[tid >> 6] = mv;
                    __syncthreads();
                    float m = fmaxf(wms[hh * 2], wms[hh * 2 + 1]);
                    float ev = __expf(lv - m);
                    float sv = wave_sum(ev);
                    if ((tid & 63) == 0) wss[tid >> 6] = sv;
                    lge[hh * 128 + k] = ev;
                    __syncthreads();
                    if (tid < 8) {
                        int bc = b * 16 + r;
                        csf(A.Pm2 + bc * 8 + tid, fmaxf(wms[tid * 2], wms[tid * 2 + 1]));
                        csf(A.Ps2 + bc * 8 + tid, wss[tid * 2] + wss[tid * 2 + 1]);
                    }
                }
                __syncthreads();
                {   // z = sum_k ev * enc_k (LDS)
                    int hz = tid >> 7, ii = tid & 127;
                    f32x4 z = {0.f, 0.f, 0.f, 0.f};
                    const ushort_t* ep2 = encL + ii * 4;
                    const float* le = lge + hz * 128;
                    #pragma unroll 4
                    for (int k = 0; k < 128; k++) {
                        float ev = le[k];
                        us4 e4 = *(const us4*)(ep2 + k * 512);
                        z[0] += ev * bf2f(e4[0]); z[1] += ev * bf2f(e4[1]);
                        z[2] += ev * bf2f(e4[2]); z[3] += ev * bf2f(e4[3]);
                    }
                    float* dst = A.Pz + ((size_t)((b * 16 + r) * 8 + hz)) * 512 + ii * 4;
                    csf2(dst, z[0], z[1]);
                    csf2(dst + 2, z[2], z[3]);
                }
            }
            gbar(bar, b);

            // ------------ S6: combine chunks + Wv slice --------------------
            {
                int h = r >> 1, half = r & 1;
                float* zs = sm;            // 512
                float* zs2 = sm + 512;     // 2048 (4 quarters)
                float* ecs = sm + 2560;    // 17
                float* part = sm + 2624;   // 512
                if (tid < 16) {
                    float mcv = clf(A.Pm2 + (b * 16 + tid) * 8 + h);
                    float mm = mcv;
                    mm = fmaxf(mm, __shfl_xor(mm, 1));
                    mm = fmaxf(mm, __shfl_xor(mm, 2));
                    mm = fmaxf(mm, __shfl_xor(mm, 4));
                    mm = fmaxf(mm, __shfl_xor(mm, 8));
                    float ec = __expf(mcv - mm);
                    float sv = ec * clf(A.Ps2 + (b * 16 + tid) * 8 + h);
                    sv += __shfl_xor(sv, 1); sv += __shfl_xor(sv, 2);
                    sv += __shfl_xor(sv, 4); sv += __shfl_xor(sv, 8);
                    ecs[tid] = ec;
                    if (tid == 0) ecs[16] = 1.f / sv;
                }
                __syncthreads();
                {   // 4 quarters x 256 col-pairs, clf2 loads
                    int cp = (tid & 255) * 2, qtr = tid >> 8;
                    float a0 = 0.f, a1 = 0.f;
                    #pragma unroll
                    for (int j = 0; j < 4; j++) {
                        int cc = qtr * 4 + j;
                        float2 v = clf2(A.Pz + ((size_t)(b * 16 + cc) * 8 + h) * 512 + cp);
                        a0 += ecs[cc] * v.x; a1 += ecs[cc] * v.y;
                    }
                    zs2[qtr * 512 + cp] = a0;
                    zs2[qtr * 512 + cp + 1] = a1;
                }
                __syncthreads();
                if (tid < 512)
                    zs[tid] = (zs2[tid] + zs2[512 + tid] + zs2[1024 + tid]
                             + zs2[1536 + tid]) * ecs[16];
                __syncthreads();
                gemv_all<8, 512>(zs, A.crossW + ((size_t)(l * 4 + 2)) * 262144,
                                 512, h * 64 + half * 32, part);
                if (tid < 32) {
                    int col = h * 64 + half * 32 + tid;
                    csf(A.attnb + (size_t)b * 512 + col,
                        gemv_allr<8>(part) + A.crossB[(l * 4 + 2) * 512 + col]);
                }
            }
            gbar(bar, b);

            // ------------ S7: y2 slice = attnb@Wco + bco + lny1 ------------
            {
                float* xa = sm;            // 512
                float* part = sm + 512;    // 512
                if (tid < 256) {
                    float2 v = clf2(A.attnb + (size_t)b * 512 + tid * 2);
                    xa[tid * 2] = v.x; xa[tid * 2 + 1] = v.y;
                }
                __syncthreads();
                gemv_all<8, 512>(xa, A.crossW + ((size_t)(l * 4 + 3)) * 262144,
                                 512, r * 32, part);
                if (tid < 32) {
                    int col = r * 32 + tid;
                    csf(A.y2 + (size_t)b * 512 + col,
                        gemv_allr<8>(part) + A.crossB[(l * 4 + 3) * 512 + col]
                        + clf(A.lny1 + (size_t)b * 512 + col));
                }
            }
            gbar(bar, b);

            // ------------ S8: tmpb slice (128 cols) = relu(LN(y2)@W1) ------
            {
                float* xsw = sm;           // 512
                float* red = sm + 512;     // 16
                float* part = sm + 1024;   // 2048 (NCQ=32)
                ln512b(A.y2 + (size_t)b * 512, A.lng + (l * 3 + 1) * 512,
                       A.lnb + (l * 3 + 1) * 512, 1, xsw, red);
                if (r == 0 && tid < 512)
                    csf(A.lny2 + (size_t)b * 512 + tid, xsw[tid]);
                gemv_all<32, 512>(xsw, A.fW1 + (size_t)l * 512 * 2048,
                                  2048, r * 128, part);
                if (tid < 128) {
                    int col = r * 128 + tid;
                    csf(A.tmpb + (size_t)b * 2048 + col,
                        fmaxf(gemv_allr<32>(part) + A.fb1[l * 2048 + col], 0.f));
                }
            }
            gbar(bar, b);

            // ------------ S9: y3 slice = tmpb@W2 + b2 + lny2 ---------------
            {
                float* ts = sm;            // 2048
                float* part = sm + 2048;   // 512
                {
                    float2 v = clf2(A.tmpb + (size_t)b * 2048 + tid * 2);
                    ts[tid * 2] = v.x; ts[tid * 2 + 1] = v.y;
                }
                __syncthreads();
                gemv_all<8, 2048>(ts, A.fW2 + (size_t)l * 2048 * 512,
                                  512, r * 32, part);
                if (tid < 32) {
                    int col = r * 32 + tid;
                    csf(A.y3 + (size_t)b * 512 + col,
                        gemv_allr<8>(part) + A.fb2[l * 512 + col]
                        + clf(A.lny2 + (size_t)b * 512 + col));
                }
            }
            gbar(bar, b);
        } // l

        // ---------------- S_out: logits slice (16 cols/role) ---------------
        {
            float* xsw = sm;           // 512
            float* red = sm + 512;     // 16
            float* part = sm + 1024;   // 256 (NCQ=4)
            ln512b(A.y3 + (size_t)b * 512, A.lng + 11 * 512, A.lnb + 11 * 512,
                   1, xsw, red);
            gemv_all<4, 512>(xsw, A.outW, 256, r * 16, part);
            if (tid < 16) {
                int col = r * 16 + tid;
                csf(A.out + (size_t)b * 4096 + t * 256 + col,
                    gemv_allr<4>(part) + A.outB[col]);
            }
        }
        gbar(bar, b);
    } // t
}

// ---------------------------------------------------------------------------

extern "C" void kernel_launch(void* const* d_in, const int* in_sizes, int n_in,
                              void* d_out, int out_size, void* d_ws, size_t ws_size,
                              hipStream_t stream) {
    Args A;
    A.enc    = (const float*)d_in[0];
    A.encIn  = (const float*)d_in[1];
    A.embW   = (const float*)d_in[2];
    A.embB   = (const float*)d_in[3];
    A.outW   = (const float*)d_in[4];
    A.outB   = (const float*)d_in[5];
    A.selfW  = (const float*)d_in[6];
    A.selfB  = (const float*)d_in[7];
    A.crossW = (const float*)d_in[8];
    A.crossB = (const float*)d_in[9];
    A.fW1    = (const float*)d_in[10];
    A.fb1    = (const float*)d_in[11];
    A.fW2    = (const float*)d_in[12];
    A.fb2    = (const float*)d_in[13];
    A.lng    = (const float*)d_in[14];
    A.lnb    = (const float*)d_in[15];
    A.out    = (float*)d_out;

    char* ws = (char*)d_ws;
    size_t off = 0;
    auto alloc = [&](size_t bytes) -> char* {
        char* p = ws + off;
        off = (off + bytes + 255) & ~(size_t)255;
        return p;
    };
    char* barrier = alloc(4096);
    A.bar = (unsigned*)barrier;
    A.x0    = (float*)alloc(16 * 512 * 4);
    A.qbuf  = (float*)alloc(16 * 512 * 4);
    A.y1    = (float*)alloc(16 * 512 * 4);
    A.y2    = (float*)alloc(16 * 512 * 4);
    A.y3    = (float*)alloc(16 * 512 * 4);
    A.attnb = (float*)alloc(16 * 512 * 4);
    A.lny1  = (float*)alloc(16 * 512 * 4);
    A.lny2  = (float*)alloc(16 * 512 * 4);
    A.qt    = (float*)alloc((size_t)16 * 8 * 512 * 4);
    A.Pm2   = (float*)alloc(16 * 16 * 8 * 4);
    A.Ps2   = (float*)alloc(16 * 16 * 8 * 4);
    A.Pz    = (float*)alloc((size_t)16 * 16 * 8 * 512 * 4);
    A.tmpb  = (float*)alloc((size_t)16 * 2048 * 4);
    A.selfK = (float*)alloc((size_t)4 * 16 * 16 * 512 * 4);
    A.selfV = (float*)alloc((size_t)4 * 16 * 16 * 512 * 4);
    if (off > ws_size) return;   // ~9 MB — always fits

    hipMemsetAsync(barrier, 0, 4096, stream);
    k_mega<<<dim3(NB), dim3(NTHR), 0, stream>>>(A);
}